// Round 9
// baseline (1000.791 us; speedup 1.0000x reference)
//
#include <hip/hip_runtime.h>
#include <hip/hip_bf16.h>
#include <math.h>

// R14: R13 + MLP W1 split into two NT4=1 sub-passes per half. R13 tripped the
// spill tripwire (WRITE 74->210MB, FETCH 47->152MB): 1024-thr workgroups get a
// hard 64-VGPR budget (4th data point), and MLP's accO[3][1] (12) persisting
// across gemm3<8,2> (~55 live) was the only phase >64. Sub-passes write
// disjoint W5 columns (no barrier between); peak MLP pressure now ~45.
// Everything else identical to R13 (2 elem/block, 34 rows, 16 waves).

#define LSEQ 17
#define RS 256   // R row stride (f32)
#define TS 264   // AC/T1 row stride (u16)
#define SS 520   // W5 row stride (u16)
#define SCS 40   // SC row stride (u16)
#define NTHR 1024
#define NWAVE 16

typedef unsigned short u16;
typedef __attribute__((ext_vector_type(8))) short short8;
typedef __attribute__((ext_vector_type(4))) float f32x4;

__device__ __forceinline__ float b2f(u16 u) {
    union { unsigned int i; float f; } x; x.i = ((unsigned int)u) << 16; return x.f;
}
__device__ __forceinline__ u16 f2b(float f) {
    union { float f; unsigned int i; } x; x.f = f;
    unsigned int r = x.i + 0x7FFFu + ((x.i >> 16) & 1u);
    return (u16)(r >> 16);
}
__device__ __forceinline__ float gelu_t(float x) {
    float u = 1.5957691216057308f * (x + 0.044715f * x * x * x);
    return x / (1.0f + __expf(-u));
}
__device__ __forceinline__ float siluf(float x) { return x / (1.0f + __expf(-x)); }
__device__ __forceinline__ float softplusf(float x) {
    return (x > 20.0f) ? x : __logf(1.0f + __expf(x));
}

__device__ const int HOPA[17]   = {0,1,4,7,2,5,8,3,6,9,11,14,10,12,15,13,16};
__device__ const int GRAPHA[17] = {0,1,4,7,2,5,8,3,6,9,12,10,13,15,11,14,16};
__device__ const int BPEI[17]   = {0,1,2,0,1,2,0,1,2,0,3,4,0,3,4,3,4};

// ws fragment offsets (elements, bf16)
#define OFF_GCN_W1   0
#define OFF_GCN_W2   131072
#define OFF_INPROJ   262144
#define OFF_OUTPROJ  524288
#define OFF_QKV      655360
#define OFF_ATTNPROJ 851968
#define OFF_MLP_W1   917504
#define OFF_MLP_W2   1179648
#define OFF_XPROJ    1441792

// dynamic LDS carve (bytes) — 2 elements: 34 rows
#define SM_R    0        // [34][256] f32 = 34816
#define SM_AC   34816    // [34][264] u16 = 17952
#define SM_T1   52768    // [34][264] u16 = 17952
#define SM_W5   70720    // [34][520] u16 = 35360
#define SM_U    106080   // union: Dbl [34][24] f32 (3264) | SC [16][17][40] u16 (21760)
#define SMEM_BYTES 127840

struct Params {
    const float *x, *gcn_ln_g, *gcn_ln_b, *gcn_w1, *gcn_b1, *gcn_w2, *gcn_b2,
                *bp_embed, *ssm_ln_g, *ssm_ln_b, *in_proj_w, *conv_w, *conv_b,
                *x_proj_w, *dt_proj_w, *dt_proj_b, *A_log, *Dp, *out_proj_w,
                *ln1_g, *ln1_b, *qkv_w, *attn_proj_w, *attn_proj_b,
                *ln2_g, *ln2_b, *mlp_w1, *mlp_b1, *mlp_w2, *mlp_b2;
    const u16* wws;
    float* out;
};

// ---------------- weight prepack: fp32 [K][N] -> bf16 B-fragments ----------------
__global__ __launch_bounds__(256) void prepack(Params P) {
    const int gid = blockIdx.x * 256 + threadIdx.x;
    const int cnt[9]  = {16384,16384,32768,16384,24576,8192,32768,32768,2048};
    const int Ns [9]  = {512,256,1024,256,768,256,1024,256,24};
    const int NPs[9]  = {512,256,1024,256,768,256,1024,256,32};
    const int offs[9] = {OFF_GCN_W1,OFF_GCN_W2,OFF_INPROJ,OFF_OUTPROJ,OFF_QKV,
                         OFF_ATTNPROJ,OFF_MLP_W1,OFF_MLP_W2,OFF_XPROJ};
    int e = 0, base = 0;
    while (e < 9 && gid >= base + cnt[e]) { base += cnt[e]; ++e; }
    if (e >= 9) return;
    const float* W;
    switch (e) {
        case 0: W = P.gcn_w1; break;      case 1: W = P.gcn_w2; break;
        case 2: W = P.in_proj_w; break;   case 3: W = P.out_proj_w; break;
        case 4: W = P.qkv_w; break;       case 5: W = P.attn_proj_w; break;
        case 6: W = P.mlp_w1; break;      case 7: W = P.mlp_w2; break;
        default: W = P.x_proj_w; break;
    }
    const int local = gid - base;
    const int lane = local & 63, frag = local >> 6;
    const int NT = NPs[e] >> 4;
    const int nt = frag % NT, kc = frag / NT;
    const int n = nt * 16 + (lane & 15);
    const int kbase = kc * 32 + (lane >> 4) * 8;
    u16 v[8];
    #pragma unroll
    for (int j = 0; j < 8; ++j)
        v[j] = (n < Ns[e]) ? f2b(W[(size_t)(kbase + j) * Ns[e] + n]) : (u16)0;
    u16* dst = (u16*)P.wws + offs[e] + ((size_t)frag * 64 + lane) * 8;
    *(short8*)dst = *(short8*)v;
}

// ---------------- MFMA helpers: 3 M-tiles over 34 packed rows, 16 waves ----------------
template <int KT, int NT4>
__device__ __forceinline__ void mfmaAcc3(f32x4 acc[3][NT4],
        const u16* __restrict__ act, int ldin,
        const u16* __restrict__ wbase, int NT, int nt0, int ntcnt, int kc0) {
    const int lane = threadIdx.x & 63, wv = threadIdx.x >> 6;
    const int m = lane & 15, quad = lane >> 4;
    const bool v2 = (m < 2);
    for (int kc = 0; kc < KT; ++kc) {
        const int ko = kc * 32 + quad * 8;
        short8 a0 = *(const short8*)(act + m * ldin + ko);
        short8 a1 = *(const short8*)(act + (16 + m) * ldin + ko);
        short8 a2 = {0,0,0,0,0,0,0,0};
        if (v2) a2 = *(const short8*)(act + (32 + m) * ldin + ko);
        #pragma unroll
        for (int i = 0; i < NT4; ++i) {
            const int ntl = wv + NWAVE * i;
            if (ntl < ntcnt) {
                const short8 b = *(const short8*)(wbase +
                    ((size_t)((kc0 + kc) * NT + nt0 + ntl) * 64 + lane) * 8);
                acc[0][i] = __builtin_amdgcn_mfma_f32_16x16x32_bf16(a0, b, acc[0][i], 0, 0, 0);
                acc[1][i] = __builtin_amdgcn_mfma_f32_16x16x32_bf16(a1, b, acc[1][i], 0, 0, 0);
                acc[2][i] = __builtin_amdgcn_mfma_f32_16x16x32_bf16(a2, b, acc[2][i], 0, 0, 0);
            }
        }
    }
}

// epi(rr, c_rel, val): rr in [0,34) packed row, c_rel relative to nt0*16.
template <int NT4, class Epi>
__device__ __forceinline__ void mfmaStore3(f32x4 acc[3][NT4], int ntcnt, Epi epi) {
    const int lane = threadIdx.x & 63, wv = threadIdx.x >> 6;
    const int col0 = lane & 15, quad = lane >> 4;
    #pragma unroll
    for (int i = 0; i < NT4; ++i) {
        const int ntl = wv + NWAVE * i;
        if (ntl < ntcnt) {
            const int cb = ntl * 16 + col0;
            #pragma unroll
            for (int r = 0; r < 4; ++r) epi(quad * 4 + r, cb, acc[0][i][r]);
            #pragma unroll
            for (int r = 0; r < 4; ++r) epi(16 + quad * 4 + r, cb, acc[1][i][r]);
            if (quad == 0) {
                epi(32, cb, acc[2][i][0]);
                epi(33, cb, acc[2][i][1]);
            }
        }
    }
}

template <int KT, int NT4, class Epi>
__device__ __forceinline__ void gemm3(const u16* act, int ldin,
        const u16* wbase, int NT, int nt0, int ntcnt, Epi epi) {
    f32x4 acc[3][NT4];
    #pragma unroll
    for (int mt = 0; mt < 3; ++mt)
        #pragma unroll
        for (int i = 0; i < NT4; ++i) acc[mt][i] = (f32x4){0.f,0.f,0.f,0.f};
    mfmaAcc3<KT, NT4>(acc, act, ldin, wbase, NT, nt0, ntcnt, 0);
    mfmaStore3<NT4>(acc, ntcnt, epi);
}

// ---------------- main fused kernel: 2 elements per block ----------------
__global__ __launch_bounds__(NTHR, 4) void fused_block(Params P) {
    extern __shared__ __align__(16) char smem[];
    float* R   = (float*)(smem + SM_R);    // [34][256] f32
    u16*   AC  = (u16*)  (smem + SM_AC);   // [34][264]
    u16*   T1  = (u16*)  (smem + SM_T1);   // [34][264]
    u16*   W5  = (u16*)  (smem + SM_W5);   // [34][520]
    float* Dbl = (float*)(smem + SM_U);    // [34][24] (mamba only)
    u16*   SC  = (u16*)  (smem + SM_U);    // [16][17][40] (attention only)

    const int tid = threadIdx.x;
    const int lane = tid & 63, wv = tid >> 6;
    const float* __restrict__ xg = P.x + (size_t)blockIdx.x * (2 * LSEQ * 256);
    const u16* __restrict__ ws = P.wws;

    // x -> R (34 contiguous rows), non-temporal float4
    for (int i4 = tid; i4 < 34 * 64; i4 += NTHR) {
        int rr = i4 >> 6, d4 = (i4 & 63) * 4;
        f32x4 v = __builtin_nontemporal_load((const f32x4*)(xg + rr * 256 + d4));
        *(f32x4*)(R + rr * RS + d4) = v;
    }
    __syncthreads();

    auto ln34 = [&](auto ld, u16* dst, const float* g, const float* bb) {
        for (int rr = wv; rr < 34; rr += NWAVE) {
            float v[4], s = 0.f, s2 = 0.f;
            #pragma unroll
            for (int j = 0; j < 4; ++j) {
                v[j] = ld(rr, lane + 64 * j);
                s += v[j]; s2 += v[j] * v[j];
            }
            #pragma unroll
            for (int m = 1; m < 64; m <<= 1) {
                s  += __shfl_xor(s, m, 64);
                s2 += __shfl_xor(s2, m, 64);
            }
            float mean = s * (1.0f / 256.0f);
            float var  = s2 * (1.0f / 256.0f) - mean * mean;
            float rstd = rsqrtf(var + 1e-5f);
            #pragma unroll
            for (int j = 0; j < 4; ++j) {
                int d = lane + 64 * j;
                dst[rr * TS + d] = f2b((v[j] - mean) * rstd * g[d] + bb[d]);
            }
        }
    };
    // sparse graph conv (49 nonzeros, compile-time weights), in place, per element
    auto gconvIP = [&](u16* buf, int stride, int width) {
        for (int u = tid; u < 2 * width; u += NTHR) {
            int e = u / width, d = u - e * width;
            u16* be = buf + e * LSEQ * stride;
            float c[17];
            #pragma unroll
            for (int j = 0; j < 17; ++j) c[j] = b2f(be[j * stride + d]);
            float o[17];
            o[0]  = 0.25f*c[0] + 0.28867513f*(c[1]+c[4]+c[7]);
            o[1]  = 0.28867513f*c[0] + 0.33333334f*(c[1]+c[2]);
            o[2]  = 0.33333334f*(c[1]+c[2]) + 0.40824829f*c[3];
            o[3]  = 0.40824829f*c[2] + 0.5f*c[3];
            o[4]  = 0.28867513f*c[0] + 0.33333334f*(c[4]+c[5]);
            o[5]  = 0.33333334f*(c[4]+c[5]) + 0.40824829f*c[6];
            o[6]  = 0.40824829f*c[5] + 0.5f*c[6];
            o[7]  = 0.28867513f*c[0] + 0.33333334f*c[7] + 0.25819889f*c[8];
            o[8]  = 0.25819889f*(c[7]+c[9]+c[11]+c[14]) + 0.2f*c[8];
            o[9]  = 0.25819889f*c[8] + 0.33333334f*c[9] + 0.40824829f*c[10];
            o[10] = 0.40824829f*c[9] + 0.5f*c[10];
            o[11] = 0.25819889f*c[8] + 0.33333334f*(c[11]+c[12]);
            o[12] = 0.33333334f*(c[11]+c[12]) + 0.40824829f*c[13];
            o[13] = 0.40824829f*c[12] + 0.5f*c[13];
            o[14] = 0.25819889f*c[8] + 0.33333334f*(c[14]+c[15]);
            o[15] = 0.33333334f*(c[14]+c[15]) + 0.40824829f*c[16];
            o[16] = 0.40824829f*c[15] + 0.5f*c[16];
            #pragma unroll
            for (int i = 0; i < 17; ++i) be[i * stride + d] = f2b(o[i]);
        }
    };

    // ---------------- GCN ----------------
    ln34([&](int rr, int d) { return R[rr * RS + d]; }, AC, P.gcn_ln_g, P.gcn_ln_b);
    __syncthreads();
    gconvIP(AC, TS, 256);
    __syncthreads();
    gemm3<8, 2>(AC, TS, ws + OFF_GCN_W1, 32, 0, 32,
        [&](int rr, int c, float v) { W5[rr * SS + c] = f2b(gelu_t(v + P.gcn_b1[c])); });
    __syncthreads();
    gconvIP(W5, SS, 512);
    __syncthreads();
    gemm3<16, 1>(W5, SS, ws + OFF_GCN_W2, 16, 0, 16,
        [&](int rr, int c, float v) { R[rr * RS + c] += v + P.gcn_b2[c]; });  // x_a
    __syncthreads();

    // ---------------- Mamba ----------------
    for (int i = tid; i < 34 * 256; i += NTHR) {
        int rr = i >> 8, d = i & 255;
        int e = (rr >= 17), l = rr - e * 17;
        AC[rr * TS + d] = f2b(R[(e * 17 + HOPA[l]) * RS + d] + P.bp_embed[BPEI[l] * 256 + d]);
    }
    __syncthreads();
    ln34([&](int rr, int d) { return b2f(AC[rr * TS + d]); }, T1, P.ssm_ln_g, P.ssm_ln_b);
    __syncthreads();
    // xm = silu(conv(in_proj[:, :512]))
    gemm3<8, 2>(T1, TS, ws + OFF_INPROJ, 64, 0, 32,
        [&](int rr, int c, float v) { W5[rr * SS + c] = f2b(siluf(v * P.conv_w[c] + P.conv_b[c])); });
    __syncthreads();
    // x_proj (N=24 padded to 32)
    gemm3<16, 1>(W5, SS, ws + OFF_XPROJ, 2, 0, 2,
        [&](int rr, int c, float v) { if (c < 24) Dbl[rr * 24 + c] = v; });
    __syncthreads();
    // selective scan: thread owns (element e, channel d) — all 1024 threads
    {
        const int e = tid >> 9, d = tid & 511;
        const int rb = e * LSEQ;
        float wdt[16];
        #pragma unroll
        for (int r = 0; r < 16; ++r) wdt[r] = P.dt_proj_w[r * 512 + d];
        const float dtb = P.dt_proj_b[d];
        float Ar[4];
        #pragma unroll
        for (int s = 0; s < 4; ++s) Ar[s] = -__expf(P.A_log[d * 4 + s]);
        const float Dpd = P.Dp[d];
        float h0 = 0.f, h1 = 0.f, h2 = 0.f, h3 = 0.f;
        for (int t = 0; t < LSEQ; ++t) {
            const float* Dv = Dbl + (rb + t) * 24;
            float a = dtb;
            #pragma unroll
            for (int r = 0; r < 16; ++r) a += Dv[r] * wdt[r];
            float dt_ = softplusf(a);
            float xm = b2f(W5[(rb + t) * SS + d]);
            float p = dt_ * xm;
            h0 = __expf(dt_ * Ar[0]) * h0 + p * Dv[16];
            h1 = __expf(dt_ * Ar[1]) * h1 + p * Dv[17];
            h2 = __expf(dt_ * Ar[2]) * h2 + p * Dv[18];
            h3 = __expf(dt_ * Ar[3]) * h3 + p * Dv[19];
            float y = h0 * Dv[20] + h1 * Dv[21] + h2 * Dv[22] + h3 * Dv[23] + Dpd * xm;
            W5[(rb + t) * SS + d] = f2b(y);
        }
    }
    __syncthreads();
    // z half of in_proj; gate y in place
    gemm3<8, 2>(T1, TS, ws + OFF_INPROJ, 64, 32, 32,
        [&](int rr, int c, float v) {
            float y = b2f(W5[rr * SS + c]);
            W5[rr * SS + c] = f2b(y * siluf(v));
        });
    __syncthreads();
    gemm3<16, 1>(W5, SS, ws + OFF_OUTPROJ, 16, 0, 16,
        [&](int rr, int c, float v) { AC[rr * TS + c] = f2b(v); });
    __syncthreads();
    // x_b = 2*x_a + scatter(mamba_out)
    for (int i = tid; i < 34 * 256; i += NTHR) {
        int rr = i >> 8, d = i & 255;
        int e = (rr >= 17), l = rr - e * 17;
        R[rr * RS + d] = 2.0f * R[rr * RS + d] + b2f(AC[(e * 17 + GRAPHA[l]) * TS + d]);
    }
    __syncthreads();

    // ---------------- Attention ----------------
    ln34([&](int rr, int d) { return R[rr * RS + d]; }, AC, P.ln1_g, P.ln1_b);
    __syncthreads();
    // QKV two passes (tiles 0-23, 24-47), NT4=2 to cap acc regs.
    // abs col cc: <256 Q -> T1; 256-767 K|V -> W5 col cc-256
    gemm3<8, 2>(AC, TS, ws + OFF_QKV, 48, 0, 24,
        [&](int rr, int c, float v) {
            if (c < 256) T1[rr * TS + c] = f2b(v);
            else         W5[rr * SS + (c - 256)] = f2b(v);
        });
    gemm3<8, 2>(AC, TS, ws + OFF_QKV, 48, 24, 24,
        [&](int rr, int c, float v) {
            W5[rr * SS + (c + 128)] = f2b(v);  // cc = c+384 -> W5 col cc-256
        });
    __syncthreads();
    // QK^T via MFMA: wave = (e, h). Q rows (T1) = A-frags, K rows (W5) = B-frags.
    // SC[wv][i][0..31], cols >16 zero (gated ka1 => exact zeros).
    {
        const int e = wv >> 3, h = wv & 7, m16 = lane & 15, quad = lane >> 4;
        const int rb = e * LSEQ;
        const u16* qb = T1 + rb * TS + h * 32 + quad * 8;
        const u16* kb = W5 + rb * SS + h * 32 + quad * 8;
        short8 qa0 = *(const short8*)(qb + m16 * TS);
        short8 ka0 = *(const short8*)(kb + m16 * SS);
        short8 qa1 = {0,0,0,0,0,0,0,0}, ka1 = {0,0,0,0,0,0,0,0};
        if (m16 == 0) {
            qa1 = *(const short8*)(qb + 16 * TS);
            ka1 = *(const short8*)(kb + 16 * SS);
        }
        f32x4 s00 = {0.f,0.f,0.f,0.f}, s01 = s00, s10 = s00, s11 = s00;
        s00 = __builtin_amdgcn_mfma_f32_16x16x32_bf16(qa0, ka0, s00, 0, 0, 0);
        s01 = __builtin_amdgcn_mfma_f32_16x16x32_bf16(qa0, ka1, s01, 0, 0, 0);
        s10 = __builtin_amdgcn_mfma_f32_16x16x32_bf16(qa1, ka0, s10, 0, 0, 0);
        s11 = __builtin_amdgcn_mfma_f32_16x16x32_bf16(qa1, ka1, s11, 0, 0, 0);
        const float sc = 0.17677669529663687f;
        u16* sh = SC + wv * 17 * SCS;
        #pragma unroll
        for (int r = 0; r < 4; ++r) {
            int i = quad * 4 + r;
            sh[i * SCS + m16]      = f2b(s00[r] * sc);
            sh[i * SCS + 16 + m16] = f2b(s01[r] * sc);
        }
        if (quad == 0) {  // row 16 = C row 0 of the qa1 tile
            sh[16 * SCS + m16]      = f2b(s10[0] * sc);
            sh[16 * SCS + 16 + m16] = f2b(s11[0] * sc);
        }
    }
    __syncthreads();
    if (tid < 272) {  // 16 units x 17 rows
        u16* row = SC + tid * SCS;
        float e[17], mx = -3.0e38f, sum = 0.f;
        #pragma unroll
        for (int j = 0; j < 17; ++j) mx = fmaxf(mx, b2f(row[j]));
        #pragma unroll
        for (int j = 0; j < 17; ++j) { e[j] = __expf(b2f(row[j]) - mx); sum += e[j]; }
        float inv = 1.0f / sum;
        #pragma unroll
        for (int j = 0; j < 17; ++j) row[j] = f2b(e[j] * inv);
    }
    __syncthreads();
    // AV via MFMA: wave = (e, h). A = att rows (SC, k-padded zeros),
    // B = V[token rb+k][chan n] from W5 cols 256..511, masked k<17 loads. o -> AC.
    {
        const int e = wv >> 3, h = wv & 7, m16 = lane & 15, quad = lane >> 4;
        const int rb = e * LSEQ;
        const u16* sh = SC + wv * 17 * SCS + quad * 8;
        short8 pa0 = *(const short8*)(sh + m16 * SCS);
        short8 pa1 = {0,0,0,0,0,0,0,0};
        if (m16 == 0) pa1 = *(const short8*)(sh + 16 * SCS);
        #pragma unroll
        for (int nt = 0; nt < 2; ++nt) {
            const u16* vbase = W5 + rb * SS + 256 + h * 32 + nt * 16 + m16;
            short8 vb;
            #pragma unroll
            for (int j = 0; j < 8; ++j) {
                int k = quad * 8 + j;
                vb[j] = (k < 17) ? (short)vbase[k * SS] : (short)0;
            }
            f32x4 o0 = {0.f,0.f,0.f,0.f}, o1 = o0;
            o0 = __builtin_amdgcn_mfma_f32_16x16x32_bf16(pa0, vb, o0, 0, 0, 0);
            o1 = __builtin_amdgcn_mfma_f32_16x16x32_bf16(pa1, vb, o1, 0, 0, 0);
            #pragma unroll
            for (int r = 0; r < 4; ++r) {
                int i = quad * 4 + r;
                AC[(rb + i) * TS + h * 32 + nt * 16 + m16] = f2b(o0[r]);
            }
            if (quad == 0)
                AC[(rb + 16) * TS + h * 32 + nt * 16 + m16] = f2b(o1[0]);
        }
    }
    __syncthreads();
    // o' = attn_proj(o) + bias
    gemm3<8, 1>(AC, TS, ws + OFF_ATTNPROJ, 16, 0, 16,
        [&](int rr, int c, float v) { T1[rr * TS + c] = f2b(v + P.attn_proj_b[c]); });
    __syncthreads();

    // ---------------- MLP + final ----------------
    ln34([&](int rr, int d) { return R[rr * RS + d] + b2f(T1[rr * TS + d]); },
         AC, P.ln2_g, P.ln2_b);
    __syncthreads();
    {
        f32x4 accO[3][1];
        #pragma unroll
        for (int mt = 0; mt < 3; ++mt) accO[mt][0] = (f32x4){0.f,0.f,0.f,0.f};
        #pragma unroll
        for (int half = 0; half < 2; ++half) {
            // W1 in two NT4=1 sub-passes (disjoint W5 cols; no barrier between)
            #pragma unroll
            for (int sub = 0; sub < 2; ++sub) {
                const int base = half * 512 + sub * 256;
                gemm3<8, 1>(AC, TS, ws + OFF_MLP_W1, 64, half * 32 + sub * 16, 16,
                    [&](int rr, int c, float v) {
                        W5[rr * SS + sub * 256 + c] = f2b(gelu_t(v + P.mlp_b1[base + c]));
                    });
            }
            __syncthreads();
            mfmaAcc3<16, 1>(accO, W5, SS, ws + OFF_MLP_W2, 16, 0, 16, half * 16);
            __syncthreads();  // W5 reused next half
        }
        float* outg = P.out + (size_t)blockIdx.x * (2 * LSEQ * 256);
        mfmaStore3<1>(accO, 16, [&](int rr, int c, float v) {
            float r = v + P.mlp_b2[c] + 2.0f * R[rr * RS + c] + b2f(T1[rr * TS + c]);
            __builtin_nontemporal_store(r, outg + rr * 256 + c);
        });
    }
}

extern "C" void kernel_launch(void* const* d_in, const int* in_sizes, int n_in,
                              void* d_out, int out_size, void* d_ws, size_t ws_size,
                              hipStream_t stream) {
    (void)in_sizes; (void)n_in; (void)ws_size; (void)out_size;
    Params P;
    P.x           = (const float*)d_in[0];
    P.gcn_ln_g    = (const float*)d_in[1];
    P.gcn_ln_b    = (const float*)d_in[2];
    P.gcn_w1      = (const float*)d_in[3];
    P.gcn_b1      = (const float*)d_in[4];
    P.gcn_w2      = (const float*)d_in[5];
    P.gcn_b2      = (const float*)d_in[6];
    P.bp_embed    = (const float*)d_in[7];
    P.ssm_ln_g    = (const float*)d_in[8];
    P.ssm_ln_b    = (const float*)d_in[9];
    P.in_proj_w   = (const float*)d_in[10];
    P.conv_w      = (const float*)d_in[11];
    P.conv_b      = (const float*)d_in[12];
    P.x_proj_w    = (const float*)d_in[13];
    P.dt_proj_w   = (const float*)d_in[14];
    P.dt_proj_b   = (const float*)d_in[15];
    P.A_log       = (const float*)d_in[16];
    P.Dp          = (const float*)d_in[17];
    P.out_proj_w  = (const float*)d_in[18];
    P.ln1_g       = (const float*)d_in[19];
    P.ln1_b       = (const float*)d_in[20];
    P.qkv_w       = (const float*)d_in[21];
    P.attn_proj_w = (const float*)d_in[22];
    P.attn_proj_b = (const float*)d_in[23];
    P.ln2_g       = (const float*)d_in[24];
    P.ln2_b       = (const float*)d_in[25];
    P.mlp_w1      = (const float*)d_in[26];
    P.mlp_b1      = (const float*)d_in[27];
    P.mlp_w2      = (const float*)d_in[28];
    P.mlp_b2      = (const float*)d_in[29];
    P.wws         = (const u16*)d_ws;
    P.out         = (float*)d_out;
    static int smem_set = 0;
    if (!smem_set) {
        hipFuncSetAttribute(reinterpret_cast<const void*>(fused_block),
                            hipFuncAttributeMaxDynamicSharedMemorySize, SMEM_BYTES);
        smem_set = 1;
    }
    hipLaunchKernelGGL(prepack, dim3(712), dim3(256), 0, stream, P);
    hipLaunchKernelGGL(fused_block, dim3(2048), dim3(NTHR), SMEM_BYTES, stream, P);
}

// Round 10
// 790.003 us; speedup vs baseline: 1.2668x; 1.2668x over previous
//
#include <hip/hip_runtime.h>
#include <hip/hip_bf16.h>
#include <math.h>

// R15: R13 with ALL GEMM phases at NT4=1 (multi-pass). R14 falsified the
// "MLP is the spill" theory (split changed nothing: WRITE 216MB, VGPR 64).
// New theory: every NT4=2 x 3-Mtile gemm3 exceeds the 64-VGPR cap once the
// compiler pipelines B-loads across kc (acc 24 + A 12 + pipelined B + epi).
// NT4=1 passes peak at ~36-48 live everywhere. QKV = 3 uniform-dest passes
// (Q|K|V), no barriers between (disjoint dests). Extra A-frag re-reads cost
// ~300cyc/pass vs ~105KB/block scratch round-trip eliminated.
// Tripwire: WRITE>120MB => spill source is scan/gconv, not GEMM.

#define LSEQ 17
#define RS 256   // R row stride (f32)
#define TS 264   // AC/T1 row stride (u16)
#define SS 520   // W5 row stride (u16)
#define SCS 40   // SC row stride (u16)
#define NTHR 1024
#define NWAVE 16

typedef unsigned short u16;
typedef __attribute__((ext_vector_type(8))) short short8;
typedef __attribute__((ext_vector_type(4))) float f32x4;

__device__ __forceinline__ float b2f(u16 u) {
    union { unsigned int i; float f; } x; x.i = ((unsigned int)u) << 16; return x.f;
}
__device__ __forceinline__ u16 f2b(float f) {
    union { float f; unsigned int i; } x; x.f = f;
    unsigned int r = x.i + 0x7FFFu + ((x.i >> 16) & 1u);
    return (u16)(r >> 16);
}
__device__ __forceinline__ float gelu_t(float x) {
    float u = 1.5957691216057308f * (x + 0.044715f * x * x * x);
    return x / (1.0f + __expf(-u));
}
__device__ __forceinline__ float siluf(float x) { return x / (1.0f + __expf(-x)); }
__device__ __forceinline__ float softplusf(float x) {
    return (x > 20.0f) ? x : __logf(1.0f + __expf(x));
}

__device__ const int HOPA[17]   = {0,1,4,7,2,5,8,3,6,9,11,14,10,12,15,13,16};
__device__ const int GRAPHA[17] = {0,1,4,7,2,5,8,3,6,9,12,10,13,15,11,14,16};
__device__ const int BPEI[17]   = {0,1,2,0,1,2,0,1,2,0,3,4,0,3,4,3,4};

// ws fragment offsets (elements, bf16)
#define OFF_GCN_W1   0
#define OFF_GCN_W2   131072
#define OFF_INPROJ   262144
#define OFF_OUTPROJ  524288
#define OFF_QKV      655360
#define OFF_ATTNPROJ 851968
#define OFF_MLP_W1   917504
#define OFF_MLP_W2   1179648
#define OFF_XPROJ    1441792

// dynamic LDS carve (bytes) — 2 elements: 34 rows
#define SM_R    0        // [34][256] f32 = 34816
#define SM_AC   34816    // [34][264] u16 = 17952
#define SM_T1   52768    // [34][264] u16 = 17952
#define SM_W5   70720    // [34][520] u16 = 35360
#define SM_U    106080   // union: Dbl [34][24] f32 (3264) | SC [16][17][40] u16 (21760)
#define SMEM_BYTES 127840

struct Params {
    const float *x, *gcn_ln_g, *gcn_ln_b, *gcn_w1, *gcn_b1, *gcn_w2, *gcn_b2,
                *bp_embed, *ssm_ln_g, *ssm_ln_b, *in_proj_w, *conv_w, *conv_b,
                *x_proj_w, *dt_proj_w, *dt_proj_b, *A_log, *Dp, *out_proj_w,
                *ln1_g, *ln1_b, *qkv_w, *attn_proj_w, *attn_proj_b,
                *ln2_g, *ln2_b, *mlp_w1, *mlp_b1, *mlp_w2, *mlp_b2;
    const u16* wws;
    float* out;
};

// ---------------- weight prepack: fp32 [K][N] -> bf16 B-fragments ----------------
__global__ __launch_bounds__(256) void prepack(Params P) {
    const int gid = blockIdx.x * 256 + threadIdx.x;
    const int cnt[9]  = {16384,16384,32768,16384,24576,8192,32768,32768,2048};
    const int Ns [9]  = {512,256,1024,256,768,256,1024,256,24};
    const int NPs[9]  = {512,256,1024,256,768,256,1024,256,32};
    const int offs[9] = {OFF_GCN_W1,OFF_GCN_W2,OFF_INPROJ,OFF_OUTPROJ,OFF_QKV,
                         OFF_ATTNPROJ,OFF_MLP_W1,OFF_MLP_W2,OFF_XPROJ};
    int e = 0, base = 0;
    while (e < 9 && gid >= base + cnt[e]) { base += cnt[e]; ++e; }
    if (e >= 9) return;
    const float* W;
    switch (e) {
        case 0: W = P.gcn_w1; break;      case 1: W = P.gcn_w2; break;
        case 2: W = P.in_proj_w; break;   case 3: W = P.out_proj_w; break;
        case 4: W = P.qkv_w; break;       case 5: W = P.attn_proj_w; break;
        case 6: W = P.mlp_w1; break;      case 7: W = P.mlp_w2; break;
        default: W = P.x_proj_w; break;
    }
    const int local = gid - base;
    const int lane = local & 63, frag = local >> 6;
    const int NT = NPs[e] >> 4;
    const int nt = frag % NT, kc = frag / NT;
    const int n = nt * 16 + (lane & 15);
    const int kbase = kc * 32 + (lane >> 4) * 8;
    u16 v[8];
    #pragma unroll
    for (int j = 0; j < 8; ++j)
        v[j] = (n < Ns[e]) ? f2b(W[(size_t)(kbase + j) * Ns[e] + n]) : (u16)0;
    u16* dst = (u16*)P.wws + offs[e] + ((size_t)frag * 64 + lane) * 8;
    *(short8*)dst = *(short8*)v;
}

// ---------------- MFMA helpers: 3 M-tiles over 34 packed rows, 16 waves, NT4=1 ----------------
template <int KT>
__device__ __forceinline__ void mfmaAcc3(f32x4 acc[3],
        const u16* __restrict__ act, int ldin,
        const u16* __restrict__ wbase, int NT, int nt0, int ntcnt, int kc0) {
    const int lane = threadIdx.x & 63, wv = threadIdx.x >> 6;
    const int m = lane & 15, quad = lane >> 4;
    const bool v2 = (m < 2);
    const int ntl = wv;
    if (ntl >= ntcnt) return;
    for (int kc = 0; kc < KT; ++kc) {
        const int ko = kc * 32 + quad * 8;
        short8 a0 = *(const short8*)(act + m * ldin + ko);
        short8 a1 = *(const short8*)(act + (16 + m) * ldin + ko);
        short8 a2 = {0,0,0,0,0,0,0,0};
        if (v2) a2 = *(const short8*)(act + (32 + m) * ldin + ko);
        const short8 b = *(const short8*)(wbase +
            ((size_t)((kc0 + kc) * NT + nt0 + ntl) * 64 + lane) * 8);
        acc[0] = __builtin_amdgcn_mfma_f32_16x16x32_bf16(a0, b, acc[0], 0, 0, 0);
        acc[1] = __builtin_amdgcn_mfma_f32_16x16x32_bf16(a1, b, acc[1], 0, 0, 0);
        acc[2] = __builtin_amdgcn_mfma_f32_16x16x32_bf16(a2, b, acc[2], 0, 0, 0);
    }
}

// epi(rr, c_rel, val): rr in [0,34) packed row, c_rel relative to nt0*16.
template <class Epi>
__device__ __forceinline__ void mfmaStore3(f32x4 acc[3], int ntcnt, Epi epi) {
    const int lane = threadIdx.x & 63, wv = threadIdx.x >> 6;
    const int col0 = lane & 15, quad = lane >> 4;
    const int ntl = wv;
    if (ntl >= ntcnt) return;
    const int cb = ntl * 16 + col0;
    #pragma unroll
    for (int r = 0; r < 4; ++r) epi(quad * 4 + r, cb, acc[0][r]);
    #pragma unroll
    for (int r = 0; r < 4; ++r) epi(16 + quad * 4 + r, cb, acc[1][r]);
    if (quad == 0) {
        epi(32, cb, acc[2][0]);
        epi(33, cb, acc[2][1]);
    }
}

template <int KT, class Epi>
__device__ __forceinline__ void gemm3(const u16* act, int ldin,
        const u16* wbase, int NT, int nt0, int ntcnt, Epi epi) {
    f32x4 acc[3];
    #pragma unroll
    for (int mt = 0; mt < 3; ++mt) acc[mt] = (f32x4){0.f,0.f,0.f,0.f};
    mfmaAcc3<KT>(acc, act, ldin, wbase, NT, nt0, ntcnt, 0);
    mfmaStore3(acc, ntcnt, epi);
}

// ---------------- main fused kernel: 2 elements per block ----------------
__global__ __launch_bounds__(NTHR, 4) void fused_block(Params P) {
    extern __shared__ __align__(16) char smem[];
    float* R   = (float*)(smem + SM_R);    // [34][256] f32
    u16*   AC  = (u16*)  (smem + SM_AC);   // [34][264]
    u16*   T1  = (u16*)  (smem + SM_T1);   // [34][264]
    u16*   W5  = (u16*)  (smem + SM_W5);   // [34][520]
    float* Dbl = (float*)(smem + SM_U);    // [34][24] (mamba only)
    u16*   SC  = (u16*)  (smem + SM_U);    // [16][17][40] (attention only)

    const int tid = threadIdx.x;
    const int lane = tid & 63, wv = tid >> 6;
    const float* __restrict__ xg = P.x + (size_t)blockIdx.x * (2 * LSEQ * 256);
    const u16* __restrict__ ws = P.wws;

    // x -> R (34 contiguous rows), non-temporal float4
    for (int i4 = tid; i4 < 34 * 64; i4 += NTHR) {
        int rr = i4 >> 6, d4 = (i4 & 63) * 4;
        f32x4 v = __builtin_nontemporal_load((const f32x4*)(xg + rr * 256 + d4));
        *(f32x4*)(R + rr * RS + d4) = v;
    }
    __syncthreads();

    auto ln34 = [&](auto ld, u16* dst, const float* g, const float* bb) {
        for (int rr = wv; rr < 34; rr += NWAVE) {
            float v[4], s = 0.f, s2 = 0.f;
            #pragma unroll
            for (int j = 0; j < 4; ++j) {
                v[j] = ld(rr, lane + 64 * j);
                s += v[j]; s2 += v[j] * v[j];
            }
            #pragma unroll
            for (int m = 1; m < 64; m <<= 1) {
                s  += __shfl_xor(s, m, 64);
                s2 += __shfl_xor(s2, m, 64);
            }
            float mean = s * (1.0f / 256.0f);
            float var  = s2 * (1.0f / 256.0f) - mean * mean;
            float rstd = rsqrtf(var + 1e-5f);
            #pragma unroll
            for (int j = 0; j < 4; ++j) {
                int d = lane + 64 * j;
                dst[rr * TS + d] = f2b((v[j] - mean) * rstd * g[d] + bb[d]);
            }
        }
    };
    // sparse graph conv (49 nonzeros, compile-time weights), in place, per element
    auto gconvIP = [&](u16* buf, int stride, int width) {
        for (int u = tid; u < 2 * width; u += NTHR) {
            int e = u / width, d = u - e * width;
            u16* be = buf + e * LSEQ * stride;
            float c[17];
            #pragma unroll
            for (int j = 0; j < 17; ++j) c[j] = b2f(be[j * stride + d]);
            float o[17];
            o[0]  = 0.25f*c[0] + 0.28867513f*(c[1]+c[4]+c[7]);
            o[1]  = 0.28867513f*c[0] + 0.33333334f*(c[1]+c[2]);
            o[2]  = 0.33333334f*(c[1]+c[2]) + 0.40824829f*c[3];
            o[3]  = 0.40824829f*c[2] + 0.5f*c[3];
            o[4]  = 0.28867513f*c[0] + 0.33333334f*(c[4]+c[5]);
            o[5]  = 0.33333334f*(c[4]+c[5]) + 0.40824829f*c[6];
            o[6]  = 0.40824829f*c[5] + 0.5f*c[6];
            o[7]  = 0.28867513f*c[0] + 0.33333334f*c[7] + 0.25819889f*c[8];
            o[8]  = 0.25819889f*(c[7]+c[9]+c[11]+c[14]) + 0.2f*c[8];
            o[9]  = 0.25819889f*c[8] + 0.33333334f*c[9] + 0.40824829f*c[10];
            o[10] = 0.40824829f*c[9] + 0.5f*c[10];
            o[11] = 0.25819889f*c[8] + 0.33333334f*(c[11]+c[12]);
            o[12] = 0.33333334f*(c[11]+c[12]) + 0.40824829f*c[13];
            o[13] = 0.40824829f*c[12] + 0.5f*c[13];
            o[14] = 0.25819889f*c[8] + 0.33333334f*(c[14]+c[15]);
            o[15] = 0.33333334f*(c[14]+c[15]) + 0.40824829f*c[16];
            o[16] = 0.40824829f*c[15] + 0.5f*c[16];
            #pragma unroll
            for (int i = 0; i < 17; ++i) be[i * stride + d] = f2b(o[i]);
        }
    };

    // ---------------- GCN ----------------
    ln34([&](int rr, int d) { return R[rr * RS + d]; }, AC, P.gcn_ln_g, P.gcn_ln_b);
    __syncthreads();
    gconvIP(AC, TS, 256);
    __syncthreads();
    // GCN W1 (NT=32): two NT4=1 passes, disjoint W5 cols
    gemm3<8>(AC, TS, ws + OFF_GCN_W1, 32, 0, 16,
        [&](int rr, int c, float v) { W5[rr * SS + c] = f2b(gelu_t(v + P.gcn_b1[c])); });
    gemm3<8>(AC, TS, ws + OFF_GCN_W1, 32, 16, 16,
        [&](int rr, int c, float v) { W5[rr * SS + 256 + c] = f2b(gelu_t(v + P.gcn_b1[256 + c])); });
    __syncthreads();
    gconvIP(W5, SS, 512);
    __syncthreads();
    gemm3<16>(W5, SS, ws + OFF_GCN_W2, 16, 0, 16,
        [&](int rr, int c, float v) { R[rr * RS + c] += v + P.gcn_b2[c]; });  // x_a
    __syncthreads();

    // ---------------- Mamba ----------------
    for (int i = tid; i < 34 * 256; i += NTHR) {
        int rr = i >> 8, d = i & 255;
        int e = (rr >= 17), l = rr - e * 17;
        AC[rr * TS + d] = f2b(R[(e * 17 + HOPA[l]) * RS + d] + P.bp_embed[BPEI[l] * 256 + d]);
    }
    __syncthreads();
    ln34([&](int rr, int d) { return b2f(AC[rr * TS + d]); }, T1, P.ssm_ln_g, P.ssm_ln_b);
    __syncthreads();
    // xm = silu(conv(in_proj[:, :512])): two NT4=1 passes
    gemm3<8>(T1, TS, ws + OFF_INPROJ, 64, 0, 16,
        [&](int rr, int c, float v) { W5[rr * SS + c] = f2b(siluf(v * P.conv_w[c] + P.conv_b[c])); });
    gemm3<8>(T1, TS, ws + OFF_INPROJ, 64, 16, 16,
        [&](int rr, int c, float v) { W5[rr * SS + 256 + c] = f2b(siluf(v * P.conv_w[256 + c] + P.conv_b[256 + c])); });
    __syncthreads();
    // x_proj (N=24 padded to 32)
    gemm3<16>(W5, SS, ws + OFF_XPROJ, 2, 0, 2,
        [&](int rr, int c, float v) { if (c < 24) Dbl[rr * 24 + c] = v; });
    __syncthreads();
    // selective scan: thread owns (element e, channel d) — all 1024 threads
    {
        const int e = tid >> 9, d = tid & 511;
        const int rb = e * LSEQ;
        float wdt[16];
        #pragma unroll
        for (int r = 0; r < 16; ++r) wdt[r] = P.dt_proj_w[r * 512 + d];
        const float dtb = P.dt_proj_b[d];
        float Ar[4];
        #pragma unroll
        for (int s = 0; s < 4; ++s) Ar[s] = -__expf(P.A_log[d * 4 + s]);
        const float Dpd = P.Dp[d];
        float h0 = 0.f, h1 = 0.f, h2 = 0.f, h3 = 0.f;
        for (int t = 0; t < LSEQ; ++t) {
            const float* Dv = Dbl + (rb + t) * 24;
            float a = dtb;
            #pragma unroll
            for (int r = 0; r < 16; ++r) a += Dv[r] * wdt[r];
            float dt_ = softplusf(a);
            float xm = b2f(W5[(rb + t) * SS + d]);
            float p = dt_ * xm;
            h0 = __expf(dt_ * Ar[0]) * h0 + p * Dv[16];
            h1 = __expf(dt_ * Ar[1]) * h1 + p * Dv[17];
            h2 = __expf(dt_ * Ar[2]) * h2 + p * Dv[18];
            h3 = __expf(dt_ * Ar[3]) * h3 + p * Dv[19];
            float y = h0 * Dv[20] + h1 * Dv[21] + h2 * Dv[22] + h3 * Dv[23] + Dpd * xm;
            W5[(rb + t) * SS + d] = f2b(y);
        }
    }
    __syncthreads();
    // z half of in_proj; gate y in place: two NT4=1 passes
    gemm3<8>(T1, TS, ws + OFF_INPROJ, 64, 32, 16,
        [&](int rr, int c, float v) {
            float y = b2f(W5[rr * SS + c]);
            W5[rr * SS + c] = f2b(y * siluf(v));
        });
    gemm3<8>(T1, TS, ws + OFF_INPROJ, 64, 48, 16,
        [&](int rr, int c, float v) {
            float y = b2f(W5[rr * SS + 256 + c]);
            W5[rr * SS + 256 + c] = f2b(y * siluf(v));
        });
    __syncthreads();
    gemm3<16>(W5, SS, ws + OFF_OUTPROJ, 16, 0, 16,
        [&](int rr, int c, float v) { AC[rr * TS + c] = f2b(v); });
    __syncthreads();
    // x_b = 2*x_a + scatter(mamba_out)
    for (int i = tid; i < 34 * 256; i += NTHR) {
        int rr = i >> 8, d = i & 255;
        int e = (rr >= 17), l = rr - e * 17;
        R[rr * RS + d] = 2.0f * R[rr * RS + d] + b2f(AC[(e * 17 + GRAPHA[l]) * TS + d]);
    }
    __syncthreads();

    // ---------------- Attention ----------------
    ln34([&](int rr, int d) { return R[rr * RS + d]; }, AC, P.ln1_g, P.ln1_b);
    __syncthreads();
    // QKV: three NT4=1 passes with uniform destinations (Q->T1, K->W5[0:256),
    // V->W5[256:512)). Disjoint dests, same A source: no barriers between.
    gemm3<8>(AC, TS, ws + OFF_QKV, 48, 0, 16,
        [&](int rr, int c, float v) { T1[rr * TS + c] = f2b(v); });
    gemm3<8>(AC, TS, ws + OFF_QKV, 48, 16, 16,
        [&](int rr, int c, float v) { W5[rr * SS + c] = f2b(v); });
    gemm3<8>(AC, TS, ws + OFF_QKV, 48, 32, 16,
        [&](int rr, int c, float v) { W5[rr * SS + 256 + c] = f2b(v); });
    __syncthreads();
    // QK^T via MFMA: wave = (e, h). Q rows (T1) = A-frags, K rows (W5) = B-frags.
    // SC[wv][i][0..31], cols >16 zero (gated ka1 => exact zeros).
    {
        const int e = wv >> 3, h = wv & 7, m16 = lane & 15, quad = lane >> 4;
        const int rb = e * LSEQ;
        const u16* qb = T1 + rb * TS + h * 32 + quad * 8;
        const u16* kb = W5 + rb * SS + h * 32 + quad * 8;
        short8 qa0 = *(const short8*)(qb + m16 * TS);
        short8 ka0 = *(const short8*)(kb + m16 * SS);
        short8 qa1 = {0,0,0,0,0,0,0,0}, ka1 = {0,0,0,0,0,0,0,0};
        if (m16 == 0) {
            qa1 = *(const short8*)(qb + 16 * TS);
            ka1 = *(const short8*)(kb + 16 * SS);
        }
        f32x4 s00 = {0.f,0.f,0.f,0.f}, s01 = s00, s10 = s00, s11 = s00;
        s00 = __builtin_amdgcn_mfma_f32_16x16x32_bf16(qa0, ka0, s00, 0, 0, 0);
        s01 = __builtin_amdgcn_mfma_f32_16x16x32_bf16(qa0, ka1, s01, 0, 0, 0);
        s10 = __builtin_amdgcn_mfma_f32_16x16x32_bf16(qa1, ka0, s10, 0, 0, 0);
        s11 = __builtin_amdgcn_mfma_f32_16x16x32_bf16(qa1, ka1, s11, 0, 0, 0);
        const float sc = 0.17677669529663687f;
        u16* sh = SC + wv * 17 * SCS;
        #pragma unroll
        for (int r = 0; r < 4; ++r) {
            int i = quad * 4 + r;
            sh[i * SCS + m16]      = f2b(s00[r] * sc);
            sh[i * SCS + 16 + m16] = f2b(s01[r] * sc);
        }
        if (quad == 0) {  // row 16 = C row 0 of the qa1 tile
            sh[16 * SCS + m16]      = f2b(s10[0] * sc);
            sh[16 * SCS + 16 + m16] = f2b(s11[0] * sc);
        }
    }
    __syncthreads();
    if (tid < 272) {  // 16 units x 17 rows
        u16* row = SC + tid * SCS;
        float e[17], mx = -3.0e38f, sum = 0.f;
        #pragma unroll
        for (int j = 0; j < 17; ++j) mx = fmaxf(mx, b2f(row[j]));
        #pragma unroll
        for (int j = 0; j < 17; ++j) { e[j] = __expf(b2f(row[j]) - mx); sum += e[j]; }
        float inv = 1.0f / sum;
        #pragma unroll
        for (int j = 0; j < 17; ++j) row[j] = f2b(e[j] * inv);
    }
    __syncthreads();
    // AV via MFMA: wave = (e, h). A = att rows (SC, k-padded zeros),
    // B = V[token rb+k][chan n] from W5 cols 256..511, masked k<17 loads. o -> AC.
    {
        const int e = wv >> 3, h = wv & 7, m16 = lane & 15, quad = lane >> 4;
        const int rb = e * LSEQ;
        const u16* sh = SC + wv * 17 * SCS + quad * 8;
        short8 pa0 = *(const short8*)(sh + m16 * SCS);
        short8 pa1 = {0,0,0,0,0,0,0,0};
        if (m16 == 0) pa1 = *(const short8*)(sh + 16 * SCS);
        #pragma unroll
        for (int nt = 0; nt < 2; ++nt) {
            const u16* vbase = W5 + rb * SS + 256 + h * 32 + nt * 16 + m16;
            short8 vb;
            #pragma unroll
            for (int j = 0; j < 8; ++j) {
                int k = quad * 8 + j;
                vb[j] = (k < 17) ? (short)vbase[k * SS] : (short)0;
            }
            f32x4 o0 = {0.f,0.f,0.f,0.f}, o1 = o0;
            o0 = __builtin_amdgcn_mfma_f32_16x16x32_bf16(pa0, vb, o0, 0, 0, 0);
            o1 = __builtin_amdgcn_mfma_f32_16x16x32_bf16(pa1, vb, o1, 0, 0, 0);
            #pragma unroll
            for (int r = 0; r < 4; ++r) {
                int i = quad * 4 + r;
                AC[(rb + i) * TS + h * 32 + nt * 16 + m16] = f2b(o0[r]);
            }
            if (quad == 0)
                AC[(rb + 16) * TS + h * 32 + nt * 16 + m16] = f2b(o1[0]);
        }
    }
    __syncthreads();
    // o' = attn_proj(o) + bias
    gemm3<8>(AC, TS, ws + OFF_ATTNPROJ, 16, 0, 16,
        [&](int rr, int c, float v) { T1[rr * TS + c] = f2b(v + P.attn_proj_b[c]); });
    __syncthreads();

    // ---------------- MLP + final ----------------
    ln34([&](int rr, int d) { return R[rr * RS + d] + b2f(T1[rr * TS + d]); },
         AC, P.ln2_g, P.ln2_b);
    __syncthreads();
    {
        f32x4 accO[3];
        #pragma unroll
        for (int mt = 0; mt < 3; ++mt) accO[mt] = (f32x4){0.f,0.f,0.f,0.f};
        #pragma unroll
        for (int half = 0; half < 2; ++half) {
            // W1 in two NT4=1 sub-passes (disjoint W5 cols; no barrier between)
            #pragma unroll
            for (int sub = 0; sub < 2; ++sub) {
                const int base = half * 512 + sub * 256;
                gemm3<8>(AC, TS, ws + OFF_MLP_W1, 64, half * 32 + sub * 16, 16,
                    [&](int rr, int c, float v) {
                        W5[rr * SS + sub * 256 + c] = f2b(gelu_t(v + P.mlp_b1[base + c]));
                    });
            }
            __syncthreads();
            mfmaAcc3<16>(accO, W5, SS, ws + OFF_MLP_W2, 16, 0, 16, half * 16);
            __syncthreads();  // W5 reused next half
        }
        float* outg = P.out + (size_t)blockIdx.x * (2 * LSEQ * 256);
        mfmaStore3(accO, 16, [&](int rr, int c, float v) {
            float r = v + P.mlp_b2[c] + 2.0f * R[rr * RS + c] + b2f(T1[rr * TS + c]);
            __builtin_nontemporal_store(r, outg + rr * 256 + c);
        });
    }
}

extern "C" void kernel_launch(void* const* d_in, const int* in_sizes, int n_in,
                              void* d_out, int out_size, void* d_ws, size_t ws_size,
                              hipStream_t stream) {
    (void)in_sizes; (void)n_in; (void)ws_size; (void)out_size;
    Params P;
    P.x           = (const float*)d_in[0];
    P.gcn_ln_g    = (const float*)d_in[1];
    P.gcn_ln_b    = (const float*)d_in[2];
    P.gcn_w1      = (const float*)d_in[3];
    P.gcn_b1      = (const float*)d_in[4];
    P.gcn_w2      = (const float*)d_in[5];
    P.gcn_b2      = (const float*)d_in[6];
    P.bp_embed    = (const float*)d_in[7];
    P.ssm_ln_g    = (const float*)d_in[8];
    P.ssm_ln_b    = (const float*)d_in[9];
    P.in_proj_w   = (const float*)d_in[10];
    P.conv_w      = (const float*)d_in[11];
    P.conv_b      = (const float*)d_in[12];
    P.x_proj_w    = (const float*)d_in[13];
    P.dt_proj_w   = (const float*)d_in[14];
    P.dt_proj_b   = (const float*)d_in[15];
    P.A_log       = (const float*)d_in[16];
    P.Dp          = (const float*)d_in[17];
    P.out_proj_w  = (const float*)d_in[18];
    P.ln1_g       = (const float*)d_in[19];
    P.ln1_b       = (const float*)d_in[20];
    P.qkv_w       = (const float*)d_in[21];
    P.attn_proj_w = (const float*)d_in[22];
    P.attn_proj_b = (const float*)d_in[23];
    P.ln2_g       = (const float*)d_in[24];
    P.ln2_b       = (const float*)d_in[25];
    P.mlp_w1      = (const float*)d_in[26];
    P.mlp_b1      = (const float*)d_in[27];
    P.mlp_w2      = (const float*)d_in[28];
    P.mlp_b2      = (const float*)d_in[29];
    P.wws         = (const u16*)d_ws;
    P.out         = (float*)d_out;
    static int smem_set = 0;
    if (!smem_set) {
        hipFuncSetAttribute(reinterpret_cast<const void*>(fused_block),
                            hipFuncAttributeMaxDynamicSharedMemorySize, SMEM_BYTES);
        smem_set = 1;
    }
    hipLaunchKernelGGL(prepack, dim3(712), dim3(256), 0, stream, P);
    hipLaunchKernelGGL(fused_block, dim3(2048), dim3(NTHR), SMEM_BYTES, stream, P);
}

// Round 11
// 779.633 us; speedup vs baseline: 1.2837x; 1.0133x over previous
//
#include <hip/hip_runtime.h>
#include <hip/hip_bf16.h>
#include <math.h>

// R16: R15 + (1) V stored transposed (VT[256][56] u16, slot-stride 24/elem,
// slots 17-23 zeroed) so AV's B-frag is one b128 load per quad instead of 16
// masked scalar gathers with 4-way bank conflicts (quad spacing 8*SS ≡ 0 mod
// 32 banks); quad3 is compile-time zero. +28.7KB LDS -> 156.5KB (1 blk/CU).
// (2) second gconv commuted past W2: (A·h)@W2 = A·(h@W2) -> gconv on 256 cols
// not 512, with +b2 and residual fused into its store.
// R15 counters: WRITE 89MB FETCH 48MB (clean), VALU 56 / MFMA 18 / occ 47,
// bank-conflicts 4.5e7 (~10%). This cuts the worst LDS pattern + gconv VALU.

#define LSEQ 17
#define RS 256   // R row stride (f32)
#define TS 264   // AC/T1 row stride (u16)
#define SS 520   // W5 row stride (u16)
#define SCS 40   // SC row stride (u16)
#define VTS 56   // VT row stride (u16): 28 dw mod 32 -> 2-way (free)
#define NTHR 1024
#define NWAVE 16

typedef unsigned short u16;
typedef __attribute__((ext_vector_type(8))) short short8;
typedef __attribute__((ext_vector_type(4))) float f32x4;

__device__ __forceinline__ float b2f(u16 u) {
    union { unsigned int i; float f; } x; x.i = ((unsigned int)u) << 16; return x.f;
}
__device__ __forceinline__ u16 f2b(float f) {
    union { float f; unsigned int i; } x; x.f = f;
    unsigned int r = x.i + 0x7FFFu + ((x.i >> 16) & 1u);
    return (u16)(r >> 16);
}
__device__ __forceinline__ float gelu_t(float x) {
    float u = 1.5957691216057308f * (x + 0.044715f * x * x * x);
    return x / (1.0f + __expf(-u));
}
__device__ __forceinline__ float siluf(float x) { return x / (1.0f + __expf(-x)); }
__device__ __forceinline__ float softplusf(float x) {
    return (x > 20.0f) ? x : __logf(1.0f + __expf(x));
}

__device__ const int HOPA[17]   = {0,1,4,7,2,5,8,3,6,9,11,14,10,12,15,13,16};
__device__ const int GRAPHA[17] = {0,1,4,7,2,5,8,3,6,9,12,10,13,15,11,14,16};
__device__ const int BPEI[17]   = {0,1,2,0,1,2,0,1,2,0,3,4,0,3,4,3,4};

// ws fragment offsets (elements, bf16)
#define OFF_GCN_W1   0
#define OFF_GCN_W2   131072
#define OFF_INPROJ   262144
#define OFF_OUTPROJ  524288
#define OFF_QKV      655360
#define OFF_ATTNPROJ 851968
#define OFF_MLP_W1   917504
#define OFF_MLP_W2   1179648
#define OFF_XPROJ    1441792

// dynamic LDS carve (bytes) — 2 elements: 34 rows
#define SM_R    0        // [34][256] f32 = 34816
#define SM_AC   34816    // [34][264] u16 = 17952
#define SM_T1   52768    // [34][264] u16 = 17952
#define SM_W5   70720    // [34][520] u16 = 35360
#define SM_U    106080   // union: Dbl [34][24] f32 (3264) | SC [16][17][40] u16 (21760)
#define SM_VT   127840   // [256][56] u16 = 28672 (attention V^T)
#define SMEM_BYTES 156512

struct Params {
    const float *x, *gcn_ln_g, *gcn_ln_b, *gcn_w1, *gcn_b1, *gcn_w2, *gcn_b2,
                *bp_embed, *ssm_ln_g, *ssm_ln_b, *in_proj_w, *conv_w, *conv_b,
                *x_proj_w, *dt_proj_w, *dt_proj_b, *A_log, *Dp, *out_proj_w,
                *ln1_g, *ln1_b, *qkv_w, *attn_proj_w, *attn_proj_b,
                *ln2_g, *ln2_b, *mlp_w1, *mlp_b1, *mlp_w2, *mlp_b2;
    const u16* wws;
    float* out;
};

// ---------------- weight prepack: fp32 [K][N] -> bf16 B-fragments ----------------
__global__ __launch_bounds__(256) void prepack(Params P) {
    const int gid = blockIdx.x * 256 + threadIdx.x;
    const int cnt[9]  = {16384,16384,32768,16384,24576,8192,32768,32768,2048};
    const int Ns [9]  = {512,256,1024,256,768,256,1024,256,24};
    const int NPs[9]  = {512,256,1024,256,768,256,1024,256,32};
    const int offs[9] = {OFF_GCN_W1,OFF_GCN_W2,OFF_INPROJ,OFF_OUTPROJ,OFF_QKV,
                         OFF_ATTNPROJ,OFF_MLP_W1,OFF_MLP_W2,OFF_XPROJ};
    int e = 0, base = 0;
    while (e < 9 && gid >= base + cnt[e]) { base += cnt[e]; ++e; }
    if (e >= 9) return;
    const float* W;
    switch (e) {
        case 0: W = P.gcn_w1; break;      case 1: W = P.gcn_w2; break;
        case 2: W = P.in_proj_w; break;   case 3: W = P.out_proj_w; break;
        case 4: W = P.qkv_w; break;       case 5: W = P.attn_proj_w; break;
        case 6: W = P.mlp_w1; break;      case 7: W = P.mlp_w2; break;
        default: W = P.x_proj_w; break;
    }
    const int local = gid - base;
    const int lane = local & 63, frag = local >> 6;
    const int NT = NPs[e] >> 4;
    const int nt = frag % NT, kc = frag / NT;
    const int n = nt * 16 + (lane & 15);
    const int kbase = kc * 32 + (lane >> 4) * 8;
    u16 v[8];
    #pragma unroll
    for (int j = 0; j < 8; ++j)
        v[j] = (n < Ns[e]) ? f2b(W[(size_t)(kbase + j) * Ns[e] + n]) : (u16)0;
    u16* dst = (u16*)P.wws + offs[e] + ((size_t)frag * 64 + lane) * 8;
    *(short8*)dst = *(short8*)v;
}

// ---------------- MFMA helpers: 3 M-tiles over 34 packed rows, 16 waves, NT4=1 ----------------
template <int KT>
__device__ __forceinline__ void mfmaAcc3(f32x4 acc[3],
        const u16* __restrict__ act, int ldin,
        const u16* __restrict__ wbase, int NT, int nt0, int ntcnt, int kc0) {
    const int lane = threadIdx.x & 63, wv = threadIdx.x >> 6;
    const int m = lane & 15, quad = lane >> 4;
    const bool v2 = (m < 2);
    const int ntl = wv;
    if (ntl >= ntcnt) return;
    for (int kc = 0; kc < KT; ++kc) {
        const int ko = kc * 32 + quad * 8;
        short8 a0 = *(const short8*)(act + m * ldin + ko);
        short8 a1 = *(const short8*)(act + (16 + m) * ldin + ko);
        short8 a2 = {0,0,0,0,0,0,0,0};
        if (v2) a2 = *(const short8*)(act + (32 + m) * ldin + ko);
        const short8 b = *(const short8*)(wbase +
            ((size_t)((kc0 + kc) * NT + nt0 + ntl) * 64 + lane) * 8);
        acc[0] = __builtin_amdgcn_mfma_f32_16x16x32_bf16(a0, b, acc[0], 0, 0, 0);
        acc[1] = __builtin_amdgcn_mfma_f32_16x16x32_bf16(a1, b, acc[1], 0, 0, 0);
        acc[2] = __builtin_amdgcn_mfma_f32_16x16x32_bf16(a2, b, acc[2], 0, 0, 0);
    }
}

// epi(rr, c_rel, val): rr in [0,34) packed row, c_rel relative to nt0*16.
template <class Epi>
__device__ __forceinline__ void mfmaStore3(f32x4 acc[3], int ntcnt, Epi epi) {
    const int lane = threadIdx.x & 63, wv = threadIdx.x >> 6;
    const int col0 = lane & 15, quad = lane >> 4;
    const int ntl = wv;
    if (ntl >= ntcnt) return;
    const int cb = ntl * 16 + col0;
    #pragma unroll
    for (int r = 0; r < 4; ++r) epi(quad * 4 + r, cb, acc[0][r]);
    #pragma unroll
    for (int r = 0; r < 4; ++r) epi(16 + quad * 4 + r, cb, acc[1][r]);
    if (quad == 0) {
        epi(32, cb, acc[2][0]);
        epi(33, cb, acc[2][1]);
    }
}

template <int KT, class Epi>
__device__ __forceinline__ void gemm3(const u16* act, int ldin,
        const u16* wbase, int NT, int nt0, int ntcnt, Epi epi) {
    f32x4 acc[3];
    #pragma unroll
    for (int mt = 0; mt < 3; ++mt) acc[mt] = (f32x4){0.f,0.f,0.f,0.f};
    mfmaAcc3<KT>(acc, act, ldin, wbase, NT, nt0, ntcnt, 0);
    mfmaStore3(acc, ntcnt, epi);
}

// ---------------- main fused kernel: 2 elements per block ----------------
__global__ __launch_bounds__(NTHR, 4) void fused_block(Params P) {
    extern __shared__ __align__(16) char smem[];
    float* R   = (float*)(smem + SM_R);    // [34][256] f32
    u16*   AC  = (u16*)  (smem + SM_AC);   // [34][264]
    u16*   T1  = (u16*)  (smem + SM_T1);   // [34][264]
    u16*   W5  = (u16*)  (smem + SM_W5);   // [34][520]
    float* Dbl = (float*)(smem + SM_U);    // [34][24] (mamba only)
    u16*   SC  = (u16*)  (smem + SM_U);    // [16][17][40] (attention only)
    u16*   VT  = (u16*)  (smem + SM_VT);   // [256][56] (attention V^T)

    const int tid = threadIdx.x;
    const int lane = tid & 63, wv = tid >> 6;
    const float* __restrict__ xg = P.x + (size_t)blockIdx.x * (2 * LSEQ * 256);
    const u16* __restrict__ ws = P.wws;

    // x -> R (34 contiguous rows), non-temporal float4
    for (int i4 = tid; i4 < 34 * 64; i4 += NTHR) {
        int rr = i4 >> 6, d4 = (i4 & 63) * 4;
        f32x4 v = __builtin_nontemporal_load((const f32x4*)(xg + rr * 256 + d4));
        *(f32x4*)(R + rr * RS + d4) = v;
    }
    __syncthreads();

    auto ln34 = [&](auto ld, u16* dst, const float* g, const float* bb) {
        for (int rr = wv; rr < 34; rr += NWAVE) {
            float v[4], s = 0.f, s2 = 0.f;
            #pragma unroll
            for (int j = 0; j < 4; ++j) {
                v[j] = ld(rr, lane + 64 * j);
                s += v[j]; s2 += v[j] * v[j];
            }
            #pragma unroll
            for (int m = 1; m < 64; m <<= 1) {
                s  += __shfl_xor(s, m, 64);
                s2 += __shfl_xor(s2, m, 64);
            }
            float mean = s * (1.0f / 256.0f);
            float var  = s2 * (1.0f / 256.0f) - mean * mean;
            float rstd = rsqrtf(var + 1e-5f);
            #pragma unroll
            for (int j = 0; j < 4; ++j) {
                int d = lane + 64 * j;
                dst[rr * TS + d] = f2b((v[j] - mean) * rstd * g[d] + bb[d]);
            }
        }
    };
    // sparse graph conv (49 nonzeros, compile-time weights); thread owns a column.
    // ldf(e, j, d) -> float, stf(e, i, d, val)
    auto gconvCols = [&](int width, auto ldf, auto stf) {
        for (int u = tid; u < 2 * width; u += NTHR) {
            int e = u / width, d = u - e * width;
            float c[17];
            #pragma unroll
            for (int j = 0; j < 17; ++j) c[j] = ldf(e, j, d);
            float o[17];
            o[0]  = 0.25f*c[0] + 0.28867513f*(c[1]+c[4]+c[7]);
            o[1]  = 0.28867513f*c[0] + 0.33333334f*(c[1]+c[2]);
            o[2]  = 0.33333334f*(c[1]+c[2]) + 0.40824829f*c[3];
            o[3]  = 0.40824829f*c[2] + 0.5f*c[3];
            o[4]  = 0.28867513f*c[0] + 0.33333334f*(c[4]+c[5]);
            o[5]  = 0.33333334f*(c[4]+c[5]) + 0.40824829f*c[6];
            o[6]  = 0.40824829f*c[5] + 0.5f*c[6];
            o[7]  = 0.28867513f*c[0] + 0.33333334f*c[7] + 0.25819889f*c[8];
            o[8]  = 0.25819889f*(c[7]+c[9]+c[11]+c[14]) + 0.2f*c[8];
            o[9]  = 0.25819889f*c[8] + 0.33333334f*c[9] + 0.40824829f*c[10];
            o[10] = 0.40824829f*c[9] + 0.5f*c[10];
            o[11] = 0.25819889f*c[8] + 0.33333334f*(c[11]+c[12]);
            o[12] = 0.33333334f*(c[11]+c[12]) + 0.40824829f*c[13];
            o[13] = 0.40824829f*c[12] + 0.5f*c[13];
            o[14] = 0.25819889f*c[8] + 0.33333334f*(c[14]+c[15]);
            o[15] = 0.33333334f*(c[14]+c[15]) + 0.40824829f*c[16];
            o[16] = 0.40824829f*c[15] + 0.5f*c[16];
            #pragma unroll
            for (int i = 0; i < 17; ++i) stf(e, i, d, o[i]);
        }
    };

    // ---------------- GCN ----------------
    ln34([&](int rr, int d) { return R[rr * RS + d]; }, AC, P.gcn_ln_g, P.gcn_ln_b);
    __syncthreads();
    gconvCols(256,
        [&](int e, int j, int d) { return b2f(AC[(e * 17 + j) * TS + d]); },
        [&](int e, int i, int d, float v) { AC[(e * 17 + i) * TS + d] = f2b(v); });
    __syncthreads();
    // GCN W1 (NT=32): two NT4=1 passes, disjoint W5 cols
    gemm3<8>(AC, TS, ws + OFF_GCN_W1, 32, 0, 16,
        [&](int rr, int c, float v) { W5[rr * SS + c] = f2b(gelu_t(v + P.gcn_b1[c])); });
    gemm3<8>(AC, TS, ws + OFF_GCN_W1, 32, 16, 16,
        [&](int rr, int c, float v) { W5[rr * SS + 256 + c] = f2b(gelu_t(v + P.gcn_b1[256 + c])); });
    __syncthreads();
    // W2 FIRST (commuted: (A·h)@W2 = A·(h@W2)), raw result -> AC
    gemm3<16>(W5, SS, ws + OFF_GCN_W2, 16, 0, 16,
        [&](int rr, int c, float v) { AC[rr * TS + c] = f2b(v); });
    __syncthreads();
    // gconv on 256 cols, fused +b2 and residual into R (x_a)
    gconvCols(256,
        [&](int e, int j, int d) { return b2f(AC[(e * 17 + j) * TS + d]); },
        [&](int e, int i, int d, float v) { R[(e * 17 + i) * RS + d] += v + P.gcn_b2[d]; });
    __syncthreads();

    // ---------------- Mamba ----------------
    for (int i = tid; i < 34 * 256; i += NTHR) {
        int rr = i >> 8, d = i & 255;
        int e = (rr >= 17), l = rr - e * 17;
        AC[rr * TS + d] = f2b(R[(e * 17 + HOPA[l]) * RS + d] + P.bp_embed[BPEI[l] * 256 + d]);
    }
    __syncthreads();
    ln34([&](int rr, int d) { return b2f(AC[rr * TS + d]); }, T1, P.ssm_ln_g, P.ssm_ln_b);
    __syncthreads();
    // xm = silu(conv(in_proj[:, :512])): two NT4=1 passes
    gemm3<8>(T1, TS, ws + OFF_INPROJ, 64, 0, 16,
        [&](int rr, int c, float v) { W5[rr * SS + c] = f2b(siluf(v * P.conv_w[c] + P.conv_b[c])); });
    gemm3<8>(T1, TS, ws + OFF_INPROJ, 64, 16, 16,
        [&](int rr, int c, float v) { W5[rr * SS + 256 + c] = f2b(siluf(v * P.conv_w[256 + c] + P.conv_b[256 + c])); });
    __syncthreads();
    // x_proj (N=24 padded to 32)
    gemm3<16>(W5, SS, ws + OFF_XPROJ, 2, 0, 2,
        [&](int rr, int c, float v) { if (c < 24) Dbl[rr * 24 + c] = v; });
    __syncthreads();
    // selective scan: thread owns (element e, channel d) — all 1024 threads
    {
        const int e = tid >> 9, d = tid & 511;
        const int rb = e * LSEQ;
        float wdt[16];
        #pragma unroll
        for (int r = 0; r < 16; ++r) wdt[r] = P.dt_proj_w[r * 512 + d];
        const float dtb = P.dt_proj_b[d];
        float Ar[4];
        #pragma unroll
        for (int s = 0; s < 4; ++s) Ar[s] = -__expf(P.A_log[d * 4 + s]);
        const float Dpd = P.Dp[d];
        float h0 = 0.f, h1 = 0.f, h2 = 0.f, h3 = 0.f;
        for (int t = 0; t < LSEQ; ++t) {
            const float* Dv = Dbl + (rb + t) * 24;
            float a = dtb;
            #pragma unroll
            for (int r = 0; r < 16; ++r) a += Dv[r] * wdt[r];
            float dt_ = softplusf(a);
            float xm = b2f(W5[(rb + t) * SS + d]);
            float p = dt_ * xm;
            h0 = __expf(dt_ * Ar[0]) * h0 + p * Dv[16];
            h1 = __expf(dt_ * Ar[1]) * h1 + p * Dv[17];
            h2 = __expf(dt_ * Ar[2]) * h2 + p * Dv[18];
            h3 = __expf(dt_ * Ar[3]) * h3 + p * Dv[19];
            float y = h0 * Dv[20] + h1 * Dv[21] + h2 * Dv[22] + h3 * Dv[23] + Dpd * xm;
            W5[(rb + t) * SS + d] = f2b(y);
        }
    }
    __syncthreads();
    // z half of in_proj; gate y in place: two NT4=1 passes
    gemm3<8>(T1, TS, ws + OFF_INPROJ, 64, 32, 16,
        [&](int rr, int c, float v) {
            float y = b2f(W5[rr * SS + c]);
            W5[rr * SS + c] = f2b(y * siluf(v));
        });
    gemm3<8>(T1, TS, ws + OFF_INPROJ, 64, 48, 16,
        [&](int rr, int c, float v) {
            float y = b2f(W5[rr * SS + 256 + c]);
            W5[rr * SS + 256 + c] = f2b(y * siluf(v));
        });
    __syncthreads();
    gemm3<16>(W5, SS, ws + OFF_OUTPROJ, 16, 0, 16,
        [&](int rr, int c, float v) { AC[rr * TS + c] = f2b(v); });
    __syncthreads();
    // x_b = 2*x_a + scatter(mamba_out)
    for (int i = tid; i < 34 * 256; i += NTHR) {
        int rr = i >> 8, d = i & 255;
        int e = (rr >= 17), l = rr - e * 17;
        R[rr * RS + d] = 2.0f * R[rr * RS + d] + b2f(AC[(e * 17 + GRAPHA[l]) * TS + d]);
    }
    __syncthreads();

    // ---------------- Attention ----------------
    ln34([&](int rr, int d) { return R[rr * RS + d]; }, AC, P.ln1_g, P.ln1_b);
    // zero VT (pads slots 17-23/41-47 that QKV won't fill)
    for (int i = tid; i < (256 * VTS) / 2; i += NTHR)
        ((unsigned int*)VT)[i] = 0u;
    __syncthreads();
    // QKV: three NT4=1 passes (Q->T1, K->W5[0:256), V -> VT transposed).
    // Disjoint dests, same A source: no barriers between.
    gemm3<8>(AC, TS, ws + OFF_QKV, 48, 0, 16,
        [&](int rr, int c, float v) { T1[rr * TS + c] = f2b(v); });
    gemm3<8>(AC, TS, ws + OFF_QKV, 48, 16, 16,
        [&](int rr, int c, float v) { W5[rr * SS + c] = f2b(v); });
    gemm3<8>(AC, TS, ws + OFF_QKV, 48, 32, 16,
        [&](int rr, int c, float v) {
            int e2 = (rr >= 17), t = rr - e2 * 17;
            VT[c * VTS + e2 * 24 + t] = f2b(v);   // V^T: [chan][e*24 + t]
        });
    __syncthreads();
    // QK^T via MFMA: wave = (e, h). Q rows (T1) = A-frags, K rows (W5) = B-frags.
    // SC[wv][i][0..31], cols >16 zero (gated ka1 => exact zeros).
    {
        const int e = wv >> 3, h = wv & 7, m16 = lane & 15, quad = lane >> 4;
        const int rb = e * LSEQ;
        const u16* qb = T1 + rb * TS + h * 32 + quad * 8;
        const u16* kb = W5 + rb * SS + h * 32 + quad * 8;
        short8 qa0 = *(const short8*)(qb + m16 * TS);
        short8 ka0 = *(const short8*)(kb + m16 * SS);
        short8 qa1 = {0,0,0,0,0,0,0,0}, ka1 = {0,0,0,0,0,0,0,0};
        if (m16 == 0) {
            qa1 = *(const short8*)(qb + 16 * TS);
            ka1 = *(const short8*)(kb + 16 * SS);
        }
        f32x4 s00 = {0.f,0.f,0.f,0.f}, s01 = s00, s10 = s00, s11 = s00;
        s00 = __builtin_amdgcn_mfma_f32_16x16x32_bf16(qa0, ka0, s00, 0, 0, 0);
        s01 = __builtin_amdgcn_mfma_f32_16x16x32_bf16(qa0, ka1, s01, 0, 0, 0);
        s10 = __builtin_amdgcn_mfma_f32_16x16x32_bf16(qa1, ka0, s10, 0, 0, 0);
        s11 = __builtin_amdgcn_mfma_f32_16x16x32_bf16(qa1, ka1, s11, 0, 0, 0);
        const float sc = 0.17677669529663687f;
        u16* sh = SC + wv * 17 * SCS;
        #pragma unroll
        for (int r = 0; r < 4; ++r) {
            int i = quad * 4 + r;
            sh[i * SCS + m16]      = f2b(s00[r] * sc);
            sh[i * SCS + 16 + m16] = f2b(s01[r] * sc);
        }
        if (quad == 0) {  // row 16 = C row 0 of the qa1 tile
            sh[16 * SCS + m16]      = f2b(s10[0] * sc);
            sh[16 * SCS + 16 + m16] = f2b(s11[0] * sc);
        }
    }
    __syncthreads();
    if (tid < 272) {  // 16 units x 17 rows
        u16* row = SC + tid * SCS;
        float e[17], mx = -3.0e38f, sum = 0.f;
        #pragma unroll
        for (int j = 0; j < 17; ++j) mx = fmaxf(mx, b2f(row[j]));
        #pragma unroll
        for (int j = 0; j < 17; ++j) { e[j] = __expf(b2f(row[j]) - mx); sum += e[j]; }
        float inv = 1.0f / sum;
        #pragma unroll
        for (int j = 0; j < 17; ++j) row[j] = f2b(e[j] * inv);
    }
    __syncthreads();
    // AV via MFMA: wave = (e, h). A = att rows (SC, k-padded zeros),
    // B = V^T[chan][k] — one b128 per quad (quad3 zero; slots 17-23 zeroed).
    {
        const int e = wv >> 3, h = wv & 7, m16 = lane & 15, quad = lane >> 4;
        const int rb = e * LSEQ;
        const u16* sh = SC + wv * 17 * SCS + quad * 8;
        short8 pa0 = *(const short8*)(sh + m16 * SCS);
        short8 pa1 = {0,0,0,0,0,0,0,0};
        if (m16 == 0) pa1 = *(const short8*)(sh + 16 * SCS);
        #pragma unroll
        for (int nt = 0; nt < 2; ++nt) {
            const int n = h * 32 + nt * 16 + m16;
            short8 vb = {0,0,0,0,0,0,0,0};
            if (quad < 3) vb = *(const short8*)(VT + n * VTS + e * 24 + quad * 8);
            f32x4 o0 = {0.f,0.f,0.f,0.f}, o1 = o0;
            o0 = __builtin_amdgcn_mfma_f32_16x16x32_bf16(pa0, vb, o0, 0, 0, 0);
            o1 = __builtin_amdgcn_mfma_f32_16x16x32_bf16(pa1, vb, o1, 0, 0, 0);
            #pragma unroll
            for (int r = 0; r < 4; ++r) {
                int i = quad * 4 + r;
                AC[(rb + i) * TS + h * 32 + nt * 16 + m16] = f2b(o0[r]);
            }
            if (quad == 0)
                AC[(rb + 16) * TS + h * 32 + nt * 16 + m16] = f2b(o1[0]);
        }
    }
    __syncthreads();
    // o' = attn_proj(o) + bias
    gemm3<8>(AC, TS, ws + OFF_ATTNPROJ, 16, 0, 16,
        [&](int rr, int c, float v) { T1[rr * TS + c] = f2b(v + P.attn_proj_b[c]); });
    __syncthreads();

    // ---------------- MLP + final ----------------
    ln34([&](int rr, int d) { return R[rr * RS + d] + b2f(T1[rr * TS + d]); },
         AC, P.ln2_g, P.ln2_b);
    __syncthreads();
    {
        f32x4 accO[3];
        #pragma unroll
        for (int mt = 0; mt < 3; ++mt) accO[mt] = (f32x4){0.f,0.f,0.f,0.f};
        #pragma unroll
        for (int half = 0; half < 2; ++half) {
            // W1 in two NT4=1 sub-passes (disjoint W5 cols; no barrier between)
            #pragma unroll
            for (int sub = 0; sub < 2; ++sub) {
                const int base = half * 512 + sub * 256;
                gemm3<8>(AC, TS, ws + OFF_MLP_W1, 64, half * 32 + sub * 16, 16,
                    [&](int rr, int c, float v) {
                        W5[rr * SS + sub * 256 + c] = f2b(gelu_t(v + P.mlp_b1[base + c]));
                    });
            }
            __syncthreads();
            mfmaAcc3<16>(accO, W5, SS, ws + OFF_MLP_W2, 16, 0, 16, half * 16);
            __syncthreads();  // W5 reused next half
        }
        float* outg = P.out + (size_t)blockIdx.x * (2 * LSEQ * 256);
        mfmaStore3(accO, 16, [&](int rr, int c, float v) {
            float r = v + P.mlp_b2[c] + 2.0f * R[rr * RS + c] + b2f(T1[rr * TS + c]);
            __builtin_nontemporal_store(r, outg + rr * 256 + c);
        });
    }
}

extern "C" void kernel_launch(void* const* d_in, const int* in_sizes, int n_in,
                              void* d_out, int out_size, void* d_ws, size_t ws_size,
                              hipStream_t stream) {
    (void)in_sizes; (void)n_in; (void)ws_size; (void)out_size;
    Params P;
    P.x           = (const float*)d_in[0];
    P.gcn_ln_g    = (const float*)d_in[1];
    P.gcn_ln_b    = (const float*)d_in[2];
    P.gcn_w1      = (const float*)d_in[3];
    P.gcn_b1      = (const float*)d_in[4];
    P.gcn_w2      = (const float*)d_in[5];
    P.gcn_b2      = (const float*)d_in[6];
    P.bp_embed    = (const float*)d_in[7];
    P.ssm_ln_g    = (const float*)d_in[8];
    P.ssm_ln_b    = (const float*)d_in[9];
    P.in_proj_w   = (const float*)d_in[10];
    P.conv_w      = (const float*)d_in[11];
    P.conv_b      = (const float*)d_in[12];
    P.x_proj_w    = (const float*)d_in[13];
    P.dt_proj_w   = (const float*)d_in[14];
    P.dt_proj_b   = (const float*)d_in[15];
    P.A_log       = (const float*)d_in[16];
    P.Dp          = (const float*)d_in[17];
    P.out_proj_w  = (const float*)d_in[18];
    P.ln1_g       = (const float*)d_in[19];
    P.ln1_b       = (const float*)d_in[20];
    P.qkv_w       = (const float*)d_in[21];
    P.attn_proj_w = (const float*)d_in[22];
    P.attn_proj_b = (const float*)d_in[23];
    P.ln2_g       = (const float*)d_in[24];
    P.ln2_b       = (const float*)d_in[25];
    P.mlp_w1      = (const float*)d_in[26];
    P.mlp_b1      = (const float*)d_in[27];
    P.mlp_w2      = (const float*)d_in[28];
    P.mlp_b2      = (const float*)d_in[29];
    P.wws         = (const u16*)d_ws;
    P.out         = (float*)d_out;
    static int smem_set = 0;
    if (!smem_set) {
        hipFuncSetAttribute(reinterpret_cast<const void*>(fused_block),
                            hipFuncAttributeMaxDynamicSharedMemorySize, SMEM_BYTES);
        smem_set = 1;
    }
    hipLaunchKernelGGL(prepack, dim3(712), dim3(256), 0, stream, P);
    hipLaunchKernelGGL(fused_block, dim3(2048), dim3(NTHR), SMEM_BYTES, stream, P);
}

// Round 12
// 744.337 us; speedup vs baseline: 1.3445x; 1.0474x over previous
//
#include <hip/hip_runtime.h>
#include <hip/hip_bf16.h>
#include <math.h>

// R17: R16 + pass/barrier fusions (memory & spills long clean; VALU+barriers
// are what's left). (1) x-load fused with GCN-ln (global->R + ln->AC, one
// pass); (2) hop-gather+bpe fused into ssm-ln (reads R[hop]+bpe -> T1);
// (3) x_b-scatter fused into ln1 (x_b->R, ln->T1; Q retargeted to AC,
// QK^T reads Q from AC); (4) ln34 lane*4 layout -> short4 stores;
// (5) gconv split-output (2 thr/column, rows 0-8 | 9-16; was half-idle).
// R16 lesson: SQ_LDS_BANK_CONFLICT is dominated by free 2-way patterns —
// not a µs-meter. Barriers 25->22.

#define LSEQ 17
#define RS 256   // R row stride (f32)
#define TS 264   // AC/T1 row stride (u16)
#define SS 520   // W5 row stride (u16)
#define SCS 40   // SC row stride (u16)
#define VTS 56   // VT row stride (u16)
#define NTHR 1024
#define NWAVE 16

typedef unsigned short u16;
typedef __attribute__((ext_vector_type(8))) short short8;
typedef __attribute__((ext_vector_type(4))) short short4v;
typedef __attribute__((ext_vector_type(4))) float f32x4;

__device__ __forceinline__ float b2f(u16 u) {
    union { unsigned int i; float f; } x; x.i = ((unsigned int)u) << 16; return x.f;
}
__device__ __forceinline__ u16 f2b(float f) {
    union { float f; unsigned int i; } x; x.f = f;
    unsigned int r = x.i + 0x7FFFu + ((x.i >> 16) & 1u);
    return (u16)(r >> 16);
}
__device__ __forceinline__ float gelu_t(float x) {
    float u = 1.5957691216057308f * (x + 0.044715f * x * x * x);
    return x / (1.0f + __expf(-u));
}
__device__ __forceinline__ float siluf(float x) { return x / (1.0f + __expf(-x)); }
__device__ __forceinline__ float softplusf(float x) {
    return (x > 20.0f) ? x : __logf(1.0f + __expf(x));
}

__device__ const int HOPA[17]   = {0,1,4,7,2,5,8,3,6,9,11,14,10,12,15,13,16};
__device__ const int GRAPHA[17] = {0,1,4,7,2,5,8,3,6,9,12,10,13,15,11,14,16};
__device__ const int BPEI[17]   = {0,1,2,0,1,2,0,1,2,0,3,4,0,3,4,3,4};

// ws fragment offsets (elements, bf16)
#define OFF_GCN_W1   0
#define OFF_GCN_W2   131072
#define OFF_INPROJ   262144
#define OFF_OUTPROJ  524288
#define OFF_QKV      655360
#define OFF_ATTNPROJ 851968
#define OFF_MLP_W1   917504
#define OFF_MLP_W2   1179648
#define OFF_XPROJ    1441792

// dynamic LDS carve (bytes) — 2 elements: 34 rows
#define SM_R    0        // [34][256] f32 = 34816
#define SM_AC   34816    // [34][264] u16 = 17952
#define SM_T1   52768    // [34][264] u16 = 17952
#define SM_W5   70720    // [34][520] u16 = 35360
#define SM_U    106080   // union: Dbl [34][24] f32 (3264) | SC [16][17][40] u16 (21760)
#define SM_VT   127840   // [256][56] u16 = 28672 (attention V^T)
#define SMEM_BYTES 156512

struct Params {
    const float *x, *gcn_ln_g, *gcn_ln_b, *gcn_w1, *gcn_b1, *gcn_w2, *gcn_b2,
                *bp_embed, *ssm_ln_g, *ssm_ln_b, *in_proj_w, *conv_w, *conv_b,
                *x_proj_w, *dt_proj_w, *dt_proj_b, *A_log, *Dp, *out_proj_w,
                *ln1_g, *ln1_b, *qkv_w, *attn_proj_w, *attn_proj_b,
                *ln2_g, *ln2_b, *mlp_w1, *mlp_b1, *mlp_w2, *mlp_b2;
    const u16* wws;
    float* out;
};

// ---------------- weight prepack: fp32 [K][N] -> bf16 B-fragments ----------------
__global__ __launch_bounds__(256) void prepack(Params P) {
    const int gid = blockIdx.x * 256 + threadIdx.x;
    const int cnt[9]  = {16384,16384,32768,16384,24576,8192,32768,32768,2048};
    const int Ns [9]  = {512,256,1024,256,768,256,1024,256,24};
    const int NPs[9] = {512,256,1024,256,768,256,1024,256,32};
    const int offs[9] = {OFF_GCN_W1,OFF_GCN_W2,OFF_INPROJ,OFF_OUTPROJ,OFF_QKV,
                         OFF_ATTNPROJ,OFF_MLP_W1,OFF_MLP_W2,OFF_XPROJ};
    int e = 0, base = 0;
    while (e < 9 && gid >= base + cnt[e]) { base += cnt[e]; ++e; }
    if (e >= 9) return;
    const float* W;
    switch (e) {
        case 0: W = P.gcn_w1; break;      case 1: W = P.gcn_w2; break;
        case 2: W = P.in_proj_w; break;   case 3: W = P.out_proj_w; break;
        case 4: W = P.qkv_w; break;       case 5: W = P.attn_proj_w; break;
        case 6: W = P.mlp_w1; break;      case 7: W = P.mlp_w2; break;
        default: W = P.x_proj_w; break;
    }
    const int local = gid - base;
    const int lane = local & 63, frag = local >> 6;
    const int NT = NPs[e] >> 4;
    const int nt = frag % NT, kc = frag / NT;
    const int n = nt * 16 + (lane & 15);
    const int kbase = kc * 32 + (lane >> 4) * 8;
    u16 v[8];
    #pragma unroll
    for (int j = 0; j < 8; ++j)
        v[j] = (n < Ns[e]) ? f2b(W[(size_t)(kbase + j) * Ns[e] + n]) : (u16)0;
    u16* dst = (u16*)P.wws + offs[e] + ((size_t)frag * 64 + lane) * 8;
    *(short8*)dst = *(short8*)v;
}

// ---------------- MFMA helpers: 3 M-tiles over 34 packed rows, 16 waves, NT4=1 ----------------
template <int KT>
__device__ __forceinline__ void mfmaAcc3(f32x4 acc[3],
        const u16* __restrict__ act, int ldin,
        const u16* __restrict__ wbase, int NT, int nt0, int ntcnt, int kc0) {
    const int lane = threadIdx.x & 63, wv = threadIdx.x >> 6;
    const int m = lane & 15, quad = lane >> 4;
    const bool v2 = (m < 2);
    const int ntl = wv;
    if (ntl >= ntcnt) return;
    for (int kc = 0; kc < KT; ++kc) {
        const int ko = kc * 32 + quad * 8;
        short8 a0 = *(const short8*)(act + m * ldin + ko);
        short8 a1 = *(const short8*)(act + (16 + m) * ldin + ko);
        short8 a2 = {0,0,0,0,0,0,0,0};
        if (v2) a2 = *(const short8*)(act + (32 + m) * ldin + ko);
        const short8 b = *(const short8*)(wbase +
            ((size_t)((kc0 + kc) * NT + nt0 + ntl) * 64 + lane) * 8);
        acc[0] = __builtin_amdgcn_mfma_f32_16x16x32_bf16(a0, b, acc[0], 0, 0, 0);
        acc[1] = __builtin_amdgcn_mfma_f32_16x16x32_bf16(a1, b, acc[1], 0, 0, 0);
        acc[2] = __builtin_amdgcn_mfma_f32_16x16x32_bf16(a2, b, acc[2], 0, 0, 0);
    }
}

// epi(rr, c_rel, val): rr in [0,34) packed row, c_rel relative to nt0*16.
template <class Epi>
__device__ __forceinline__ void mfmaStore3(f32x4 acc[3], int ntcnt, Epi epi) {
    const int lane = threadIdx.x & 63, wv = threadIdx.x >> 6;
    const int col0 = lane & 15, quad = lane >> 4;
    const int ntl = wv;
    if (ntl >= ntcnt) return;
    const int cb = ntl * 16 + col0;
    #pragma unroll
    for (int r = 0; r < 4; ++r) epi(quad * 4 + r, cb, acc[0][r]);
    #pragma unroll
    for (int r = 0; r < 4; ++r) epi(16 + quad * 4 + r, cb, acc[1][r]);
    if (quad == 0) {
        epi(32, cb, acc[2][0]);
        epi(33, cb, acc[2][1]);
    }
}

template <int KT, class Epi>
__device__ __forceinline__ void gemm3(const u16* act, int ldin,
        const u16* wbase, int NT, int nt0, int ntcnt, Epi epi) {
    f32x4 acc[3];
    #pragma unroll
    for (int mt = 0; mt < 3; ++mt) acc[mt] = (f32x4){0.f,0.f,0.f,0.f};
    mfmaAcc3<KT>(acc, act, ldin, wbase, NT, nt0, ntcnt, 0);
    mfmaStore3(acc, ntcnt, epi);
}

// ---------------- main fused kernel: 2 elements per block ----------------
__global__ __launch_bounds__(NTHR, 4) void fused_block(Params P) {
    extern __shared__ __align__(16) char smem[];
    float* R   = (float*)(smem + SM_R);    // [34][256] f32
    u16*   AC  = (u16*)  (smem + SM_AC);   // [34][264]
    u16*   T1  = (u16*)  (smem + SM_T1);   // [34][264]
    u16*   W5  = (u16*)  (smem + SM_W5);   // [34][520]
    float* Dbl = (float*)(smem + SM_U);    // [34][24] (mamba only)
    u16*   SC  = (u16*)  (smem + SM_U);    // [16][17][40] (attention only)
    u16*   VT  = (u16*)  (smem + SM_VT);   // [256][56] (attention V^T)

    const int tid = threadIdx.x;
    const int lane = tid & 63, wv = tid >> 6;
    const float* __restrict__ xg = P.x + (size_t)blockIdx.x * (2 * LSEQ * 256);
    const u16* __restrict__ ws = P.wws;

    // ln core: lane owns 4 consecutive cols d0..d0+3; v[] given, writes short4.
    auto lnStore = [&](float v[4], u16* dst, int rr, int d0,
                       const float* g, const float* bb) {
        float s = v[0] + v[1] + v[2] + v[3];
        float s2 = v[0]*v[0] + v[1]*v[1] + v[2]*v[2] + v[3]*v[3];
        #pragma unroll
        for (int m = 1; m < 64; m <<= 1) {
            s  += __shfl_xor(s, m, 64);
            s2 += __shfl_xor(s2, m, 64);
        }
        float mean = s * (1.0f / 256.0f);
        float var  = s2 * (1.0f / 256.0f) - mean * mean;
        float rstd = rsqrtf(var + 1e-5f);
        u16 o[4];
        #pragma unroll
        for (int j = 0; j < 4; ++j)
            o[j] = f2b((v[j] - mean) * rstd * g[d0 + j] + bb[d0 + j]);
        *(short4v*)(dst + rr * TS + d0) = *(short4v*)o;
    };
    auto ln34 = [&](auto ld, u16* dst, const float* g, const float* bb) {
        const int d0 = lane * 4;
        for (int rr = wv; rr < 34; rr += NWAVE) {
            float v[4];
            #pragma unroll
            for (int j = 0; j < 4; ++j) v[j] = ld(rr, d0 + j);
            lnStore(v, dst, rr, d0, g, bb);
        }
    };
    // sparse graph conv (49 nonzeros, compile-time weights); 2 threads/column
    // (half 0 -> rows 0-8, half 1 -> rows 9-16). ldf(e,j,d), stf(e,i,d,val).
    auto gconvCols = [&](auto ldf, auto stf) {
        const int u = tid & 511, half = tid >> 9;
        const int e = u >> 8, d = u & 255;
        float c[17];
        #pragma unroll
        for (int j = 0; j < 17; ++j) c[j] = ldf(e, j, d);
        if (half == 0) {
            stf(e, 0, d, 0.25f*c[0] + 0.28867513f*(c[1]+c[4]+c[7]));
            stf(e, 1, d, 0.28867513f*c[0] + 0.33333334f*(c[1]+c[2]));
            stf(e, 2, d, 0.33333334f*(c[1]+c[2]) + 0.40824829f*c[3]);
            stf(e, 3, d, 0.40824829f*c[2] + 0.5f*c[3]);
            stf(e, 4, d, 0.28867513f*c[0] + 0.33333334f*(c[4]+c[5]));
            stf(e, 5, d, 0.33333334f*(c[4]+c[5]) + 0.40824829f*c[6]);
            stf(e, 6, d, 0.40824829f*c[5] + 0.5f*c[6]);
            stf(e, 7, d, 0.28867513f*c[0] + 0.33333334f*c[7] + 0.25819889f*c[8]);
            stf(e, 8, d, 0.25819889f*(c[7]+c[9]+c[11]+c[14]) + 0.2f*c[8]);
        } else {
            stf(e, 9, d, 0.25819889f*c[8] + 0.33333334f*c[9] + 0.40824829f*c[10]);
            stf(e,10, d, 0.40824829f*c[9] + 0.5f*c[10]);
            stf(e,11, d, 0.25819889f*c[8] + 0.33333334f*(c[11]+c[12]));
            stf(e,12, d, 0.33333334f*(c[11]+c[12]) + 0.40824829f*c[13]);
            stf(e,13, d, 0.40824829f*c[12] + 0.5f*c[13]);
            stf(e,14, d, 0.25819889f*c[8] + 0.33333334f*(c[14]+c[15]));
            stf(e,15, d, 0.33333334f*(c[14]+c[15]) + 0.40824829f*c[16]);
            stf(e,16, d, 0.40824829f*c[15] + 0.5f*c[16]);
        }
    };

    // ---------------- P0: x -> R fused with GCN ln -> AC ----------------
    {
        const int d0 = lane * 4;
        for (int rr = wv; rr < 34; rr += NWAVE) {
            f32x4 x4 = __builtin_nontemporal_load((const f32x4*)(xg + rr * 256 + d0));
            *(f32x4*)(R + rr * RS + d0) = x4;
            float v[4] = {x4[0], x4[1], x4[2], x4[3]};
            lnStore(v, AC, rr, d0, P.gcn_ln_g, P.gcn_ln_b);
        }
    }
    __syncthreads();

    // ---------------- GCN ----------------
    gconvCols(
        [&](int e, int j, int d) { return b2f(AC[(e * 17 + j) * TS + d]); },
        [&](int e, int i, int d, float v) { AC[(e * 17 + i) * TS + d] = f2b(v); });
    __syncthreads();
    gemm3<8>(AC, TS, ws + OFF_GCN_W1, 32, 0, 16,
        [&](int rr, int c, float v) { W5[rr * SS + c] = f2b(gelu_t(v + P.gcn_b1[c])); });
    gemm3<8>(AC, TS, ws + OFF_GCN_W1, 32, 16, 16,
        [&](int rr, int c, float v) { W5[rr * SS + 256 + c] = f2b(gelu_t(v + P.gcn_b1[256 + c])); });
    __syncthreads();
    // W2 first (commuted), raw result -> AC
    gemm3<16>(W5, SS, ws + OFF_GCN_W2, 16, 0, 16,
        [&](int rr, int c, float v) { AC[rr * TS + c] = f2b(v); });
    __syncthreads();
    // gconv on 256 cols, fused +b2 and residual into R (x_a)
    gconvCols(
        [&](int e, int j, int d) { return b2f(AC[(e * 17 + j) * TS + d]); },
        [&](int e, int i, int d, float v) { R[(e * 17 + i) * RS + d] += v + P.gcn_b2[d]; });
    __syncthreads();

    // ---------------- Mamba ----------------
    // P5: hop-gather + bpe fused into ssm ln -> T1
    {
        const int d0 = lane * 4;
        for (int rr = wv; rr < 34; rr += NWAVE) {
            int e = (rr >= 17), l = rr - e * 17;
            const float* rs = R + (e * 17 + HOPA[l]) * RS;
            const float* bp = P.bp_embed + BPEI[l] * 256;
            float v[4];
            #pragma unroll
            for (int j = 0; j < 4; ++j) v[j] = rs[d0 + j] + bp[d0 + j];
            lnStore(v, T1, rr, d0, P.ssm_ln_g, P.ssm_ln_b);
        }
    }
    __syncthreads();
    // xm = silu(conv(in_proj[:, :512])): two NT4=1 passes
    gemm3<8>(T1, TS, ws + OFF_INPROJ, 64, 0, 16,
        [&](int rr, int c, float v) { W5[rr * SS + c] = f2b(siluf(v * P.conv_w[c] + P.conv_b[c])); });
    gemm3<8>(T1, TS, ws + OFF_INPROJ, 64, 16, 16,
        [&](int rr, int c, float v) { W5[rr * SS + 256 + c] = f2b(siluf(v * P.conv_w[256 + c] + P.conv_b[256 + c])); });
    __syncthreads();
    // x_proj (N=24 padded to 32)
    gemm3<16>(W5, SS, ws + OFF_XPROJ, 2, 0, 2,
        [&](int rr, int c, float v) { if (c < 24) Dbl[rr * 24 + c] = v; });
    __syncthreads();
    // selective scan: thread owns (element e, channel d)
    {
        const int e = tid >> 9, d = tid & 511;
        const int rb = e * LSEQ;
        float wdt[16];
        #pragma unroll
        for (int r = 0; r < 16; ++r) wdt[r] = P.dt_proj_w[r * 512 + d];
        const float dtb = P.dt_proj_b[d];
        float Ar[4];
        #pragma unroll
        for (int s = 0; s < 4; ++s) Ar[s] = -__expf(P.A_log[d * 4 + s]);
        const float Dpd = P.Dp[d];
        float h0 = 0.f, h1 = 0.f, h2 = 0.f, h3 = 0.f;
        for (int t = 0; t < LSEQ; ++t) {
            const float* Dv = Dbl + (rb + t) * 24;
            float a = dtb;
            #pragma unroll
            for (int r = 0; r < 16; ++r) a += Dv[r] * wdt[r];
            float dt_ = softplusf(a);
            float xm = b2f(W5[(rb + t) * SS + d]);
            float p = dt_ * xm;
            h0 = __expf(dt_ * Ar[0]) * h0 + p * Dv[16];
            h1 = __expf(dt_ * Ar[1]) * h1 + p * Dv[17];
            h2 = __expf(dt_ * Ar[2]) * h2 + p * Dv[18];
            h3 = __expf(dt_ * Ar[3]) * h3 + p * Dv[19];
            float y = h0 * Dv[20] + h1 * Dv[21] + h2 * Dv[22] + h3 * Dv[23] + Dpd * xm;
            W5[(rb + t) * SS + d] = f2b(y);
        }
    }
    __syncthreads();
    // z half of in_proj; gate y in place: two NT4=1 passes
    gemm3<8>(T1, TS, ws + OFF_INPROJ, 64, 32, 16,
        [&](int rr, int c, float v) {
            float y = b2f(W5[rr * SS + c]);
            W5[rr * SS + c] = f2b(y * siluf(v));
        });
    gemm3<8>(T1, TS, ws + OFF_INPROJ, 64, 48, 16,
        [&](int rr, int c, float v) {
            float y = b2f(W5[rr * SS + 256 + c]);
            W5[rr * SS + 256 + c] = f2b(y * siluf(v));
        });
    __syncthreads();
    gemm3<16>(W5, SS, ws + OFF_OUTPROJ, 16, 0, 16,
        [&](int rr, int c, float v) { AC[rr * TS + c] = f2b(v); });
    __syncthreads();

    // ---------------- Attention ----------------
    // P10: x_b scatter fused into ln1 -> T1 (x_b -> R); VT zeroing here too.
    {
        const int d0 = lane * 4;
        for (int rr = wv; rr < 34; rr += NWAVE) {
            int e = (rr >= 17), l = rr - e * 17;
            const u16* ms = AC + (e * 17 + GRAPHA[l]) * TS;
            float* rrow = R + rr * RS;
            float v[4];
            #pragma unroll
            for (int j = 0; j < 4; ++j) v[j] = 2.0f * rrow[d0 + j] + b2f(ms[d0 + j]);
            *(f32x4*)(rrow + d0) = (f32x4){v[0], v[1], v[2], v[3]};
            lnStore(v, T1, rr, d0, P.ln1_g, P.ln1_b);
        }
        for (int i = tid; i < (256 * VTS) / 2; i += NTHR)
            ((unsigned int*)VT)[i] = 0u;
    }
    __syncthreads();
    // QKV: three NT4=1 passes from T1 (Q->AC, K->W5[0:256), V->VT transposed).
    gemm3<8>(T1, TS, ws + OFF_QKV, 48, 0, 16,
        [&](int rr, int c, float v) { AC[rr * TS + c] = f2b(v); });
    gemm3<8>(T1, TS, ws + OFF_QKV, 48, 16, 16,
        [&](int rr, int c, float v) { W5[rr * SS + c] = f2b(v); });
    gemm3<8>(T1, TS, ws + OFF_QKV, 48, 32, 16,
        [&](int rr, int c, float v) {
            int e2 = (rr >= 17), t = rr - e2 * 17;
            VT[c * VTS + e2 * 24 + t] = f2b(v);   // V^T: [chan][e*24 + t]
        });
    __syncthreads();
    // QK^T via MFMA: wave = (e, h). Q rows (AC) = A-frags, K rows (W5) = B-frags.
    {
        const int e = wv >> 3, h = wv & 7, m16 = lane & 15, quad = lane >> 4;
        const int rb = e * LSEQ;
        const u16* qb = AC + rb * TS + h * 32 + quad * 8;
        const u16* kb = W5 + rb * SS + h * 32 + quad * 8;
        short8 qa0 = *(const short8*)(qb + m16 * TS);
        short8 ka0 = *(const short8*)(kb + m16 * SS);
        short8 qa1 = {0,0,0,0,0,0,0,0}, ka1 = {0,0,0,0,0,0,0,0};
        if (m16 == 0) {
            qa1 = *(const short8*)(qb + 16 * TS);
            ka1 = *(const short8*)(kb + 16 * SS);
        }
        f32x4 s00 = {0.f,0.f,0.f,0.f}, s01 = s00, s10 = s00, s11 = s00;
        s00 = __builtin_amdgcn_mfma_f32_16x16x32_bf16(qa0, ka0, s00, 0, 0, 0);
        s01 = __builtin_amdgcn_mfma_f32_16x16x32_bf16(qa0, ka1, s01, 0, 0, 0);
        s10 = __builtin_amdgcn_mfma_f32_16x16x32_bf16(qa1, ka0, s10, 0, 0, 0);
        s11 = __builtin_amdgcn_mfma_f32_16x16x32_bf16(qa1, ka1, s11, 0, 0, 0);
        const float sc = 0.17677669529663687f;
        u16* sh = SC + wv * 17 * SCS;
        #pragma unroll
        for (int r = 0; r < 4; ++r) {
            int i = quad * 4 + r;
            sh[i * SCS + m16]      = f2b(s00[r] * sc);
            sh[i * SCS + 16 + m16] = f2b(s01[r] * sc);
        }
        if (quad == 0) {  // row 16 = C row 0 of the qa1 tile
            sh[16 * SCS + m16]      = f2b(s10[0] * sc);
            sh[16 * SCS + 16 + m16] = f2b(s11[0] * sc);
        }
    }
    __syncthreads();
    if (tid < 272) {  // 16 units x 17 rows
        u16* row = SC + tid * SCS;
        float e[17], mx = -3.0e38f, sum = 0.f;
        #pragma unroll
        for (int j = 0; j < 17; ++j) mx = fmaxf(mx, b2f(row[j]));
        #pragma unroll
        for (int j = 0; j < 17; ++j) { e[j] = __expf(b2f(row[j]) - mx); sum += e[j]; }
        float inv = 1.0f / sum;
        #pragma unroll
        for (int j = 0; j < 17; ++j) row[j] = f2b(e[j] * inv);
    }
    __syncthreads();
    // AV via MFMA: o -> AC (Q dead after QK^T).
    {
        const int e = wv >> 3, h = wv & 7, m16 = lane & 15, quad = lane >> 4;
        const int rb = e * LSEQ;
        const u16* sh = SC + wv * 17 * SCS + quad * 8;
        short8 pa0 = *(const short8*)(sh + m16 * SCS);
        short8 pa1 = {0,0,0,0,0,0,0,0};
        if (m16 == 0) pa1 = *(const short8*)(sh + 16 * SCS);
        #pragma unroll
        for (int nt = 0; nt < 2; ++nt) {
            const int n = h * 32 + nt * 16 + m16;
            short8 vb = {0,0,0,0,0,0,0,0};
            if (quad < 3) vb = *(const short8*)(VT + n * VTS + e * 24 + quad * 8);
            f32x4 o0 = {0.f,0.f,0.f,0.f}, o1 = o0;
            o0 = __builtin_amdgcn_mfma_f32_16x16x32_bf16(pa0, vb, o0, 0, 0, 0);
            o1 = __builtin_amdgcn_mfma_f32_16x16x32_bf16(pa1, vb, o1, 0, 0, 0);
            #pragma unroll
            for (int r = 0; r < 4; ++r) {
                int i = quad * 4 + r;
                AC[(rb + i) * TS + h * 32 + nt * 16 + m16] = f2b(o0[r]);
            }
            if (quad == 0)
                AC[(rb + 16) * TS + h * 32 + nt * 16 + m16] = f2b(o1[0]);
        }
    }
    __syncthreads();
    // o' = attn_proj(o) + bias -> T1 (ln1-out dead after QKV)
    gemm3<8>(AC, TS, ws + OFF_ATTNPROJ, 16, 0, 16,
        [&](int rr, int c, float v) { T1[rr * TS + c] = f2b(v + P.attn_proj_b[c]); });
    __syncthreads();

    // ---------------- MLP + final ----------------
    ln34([&](int rr, int d) { return R[rr * RS + d] + b2f(T1[rr * TS + d]); },
         AC, P.ln2_g, P.ln2_b);
    __syncthreads();
    {
        f32x4 accO[3];
        #pragma unroll
        for (int mt = 0; mt < 3; ++mt) accO[mt] = (f32x4){0.f,0.f,0.f,0.f};
        #pragma unroll
        for (int half = 0; half < 2; ++half) {
            #pragma unroll
            for (int sub = 0; sub < 2; ++sub) {
                const int base = half * 512 + sub * 256;
                gemm3<8>(AC, TS, ws + OFF_MLP_W1, 64, half * 32 + sub * 16, 16,
                    [&](int rr, int c, float v) {
                        W5[rr * SS + sub * 256 + c] = f2b(gelu_t(v + P.mlp_b1[base + c]));
                    });
            }
            __syncthreads();
            mfmaAcc3<16>(accO, W5, SS, ws + OFF_MLP_W2, 16, 0, 16, half * 16);
            __syncthreads();  // W5 reused next half
        }
        float* outg = P.out + (size_t)blockIdx.x * (2 * LSEQ * 256);
        mfmaStore3(accO, 16, [&](int rr, int c, float v) {
            float r = v + P.mlp_b2[c] + 2.0f * R[rr * RS + c] + b2f(T1[rr * TS + c]);
            __builtin_nontemporal_store(r, outg + rr * 256 + c);
        });
    }
}

extern "C" void kernel_launch(void* const* d_in, const int* in_sizes, int n_in,
                              void* d_out, int out_size, void* d_ws, size_t ws_size,
                              hipStream_t stream) {
    (void)in_sizes; (void)n_in; (void)ws_size; (void)out_size;
    Params P;
    P.x           = (const float*)d_in[0];
    P.gcn_ln_g    = (const float*)d_in[1];
    P.gcn_ln_b    = (const float*)d_in[2];
    P.gcn_w1      = (const float*)d_in[3];
    P.gcn_b1      = (const float*)d_in[4];
    P.gcn_w2      = (const float*)d_in[5];
    P.gcn_b2      = (const float*)d_in[6];
    P.bp_embed    = (const float*)d_in[7];
    P.ssm_ln_g    = (const float*)d_in[8];
    P.ssm_ln_b    = (const float*)d_in[9];
    P.in_proj_w   = (const float*)d_in[10];
    P.conv_w      = (const float*)d_in[11];
    P.conv_b      = (const float*)d_in[12];
    P.x_proj_w    = (const float*)d_in[13];
    P.dt_proj_w   = (const float*)d_in[14];
    P.dt_proj_b   = (const float*)d_in[15];
    P.A_log       = (const float*)d_in[16];
    P.Dp          = (const float*)d_in[17];
    P.out_proj_w  = (const float*)d_in[18];
    P.ln1_g       = (const float*)d_in[19];
    P.ln1_b       = (const float*)d_in[20];
    P.qkv_w       = (const float*)d_in[21];
    P.attn_proj_w = (const float*)d_in[22];
    P.attn_proj_b = (const float*)d_in[23];
    P.ln2_g       = (const float*)d_in[24];
    P.ln2_b       = (const float*)d_in[25];
    P.mlp_w1      = (const float*)d_in[26];
    P.mlp_b1      = (const float*)d_in[27];
    P.mlp_w2      = (const float*)d_in[28];
    P.mlp_b2      = (const float*)d_in[29];
    P.wws         = (const u16*)d_ws;
    P.out         = (float*)d_out;
    static int smem_set = 0;
    if (!smem_set) {
        hipFuncSetAttribute(reinterpret_cast<const void*>(fused_block),
                            hipFuncAttributeMaxDynamicSharedMemorySize, SMEM_BYTES);
        smem_set = 1;
    }
    hipLaunchKernelGGL(prepack, dim3(712), dim3(256), 0, stream, P);
    hipLaunchKernelGGL(fused_block, dim3(2048), dim3(NTHR), SMEM_BYTES, stream, P);
}

// Round 13
// 724.992 us; speedup vs baseline: 1.3804x; 1.0267x over previous
//
#include <hip/hip_runtime.h>
#include <hip/hip_bf16.h>
#include <math.h>

// R18: R17 + (1) NT4=2 GEMM passes with "#pragma unroll 1" on the kc loop.
// LDS-pipe accounting: NT4=1 makes all 16 waves re-read identical A-frags
// (~9.2k b128 wave-insts/block ~ 40-55% of LDS cycles). NT4=2 halves passes
// for 32-tile GEMMs (W1/inproj/gate/QKV/MLP-W1: -25% total A-insts); unroll 1
// suppresses the cross-kc B-load pipelining that spilled R13/R14 at the
// 64-VGPR cap (acc24+A12+2B8+addr ~54 < 64). Tripwire: WRITE>120MB = spills.
// (2) dt via MFMA: xproj epi -> DTI[34][32] bf16 (K-pad 0), gemm3<1,2> vs
// prepacked dt_proj_w (K=16 pad 32) -> softplus -> DTO[34][512] bf16; scan
// loses its serial 16-FMA dot + softplus + 16 LDS broadcasts per t. +1 barrier.

#define LSEQ 17
#define RS 256   // R row stride (f32)
#define TS 264   // AC/T1 row stride (u16)
#define SS 520   // W5 row stride (u16)
#define SCS 40   // SC row stride (u16)
#define VTS 56   // VT row stride (u16)
#define NTHR 1024
#define NWAVE 16

typedef unsigned short u16;
typedef __attribute__((ext_vector_type(8))) short short8;
typedef __attribute__((ext_vector_type(4))) short short4v;
typedef __attribute__((ext_vector_type(4))) float f32x4;

__device__ __forceinline__ float b2f(u16 u) {
    union { unsigned int i; float f; } x; x.i = ((unsigned int)u) << 16; return x.f;
}
__device__ __forceinline__ u16 f2b(float f) {
    union { float f; unsigned int i; } x; x.f = f;
    unsigned int r = x.i + 0x7FFFu + ((x.i >> 16) & 1u);
    return (u16)(r >> 16);
}
__device__ __forceinline__ float gelu_t(float x) {
    float u = 1.5957691216057308f * (x + 0.044715f * x * x * x);
    return x / (1.0f + __expf(-u));
}
__device__ __forceinline__ float siluf(float x) { return x / (1.0f + __expf(-x)); }
__device__ __forceinline__ float softplusf(float x) {
    return (x > 20.0f) ? x : __logf(1.0f + __expf(x));
}

__device__ const int HOPA[17]   = {0,1,4,7,2,5,8,3,6,9,11,14,10,12,15,13,16};
__device__ const int GRAPHA[17] = {0,1,4,7,2,5,8,3,6,9,12,10,13,15,11,14,16};
__device__ const int BPEI[17]   = {0,1,2,0,1,2,0,1,2,0,3,4,0,3,4,3,4};

// ws fragment offsets (elements, bf16)
#define OFF_GCN_W1   0
#define OFF_GCN_W2   131072
#define OFF_INPROJ   262144
#define OFF_OUTPROJ  524288
#define OFF_QKV      655360
#define OFF_ATTNPROJ 851968
#define OFF_MLP_W1   917504
#define OFF_MLP_W2   1179648
#define OFF_XPROJ    1441792
#define OFF_DTW      1458176   // dt_proj_w [16][512], K padded to 32

// dynamic LDS carve (bytes) — 2 elements: 34 rows
#define SM_R    0        // [34][256] f32 = 34816
#define SM_AC   34816    // [34][264] u16 = 17952
#define SM_T1   52768    // [34][264] u16 = 17952
#define SM_W5   70720    // [34][520] u16 = 35360
#define SM_U    106080   // Dbl [34][24] f32 (3264) | SC [16][17][40] u16 (attn)
#define SM_DTI  109344   // [34][32] u16 = 2176 (mamba; cols 16-31 zero)
#define SM_DTO  111520   // [34][512] u16 = 34816 (mamba)
#define SM_VT   127840   // [256][56] u16 = 28672 (attention V^T)
#define SMEM_BYTES 156512

struct Params {
    const float *x, *gcn_ln_g, *gcn_ln_b, *gcn_w1, *gcn_b1, *gcn_w2, *gcn_b2,
                *bp_embed, *ssm_ln_g, *ssm_ln_b, *in_proj_w, *conv_w, *conv_b,
                *x_proj_w, *dt_proj_w, *dt_proj_b, *A_log, *Dp, *out_proj_w,
                *ln1_g, *ln1_b, *qkv_w, *attn_proj_w, *attn_proj_b,
                *ln2_g, *ln2_b, *mlp_w1, *mlp_b1, *mlp_w2, *mlp_b2;
    const u16* wws;
    float* out;
};

// ---------------- weight prepack: fp32 [K][N] -> bf16 B-fragments ----------------
__global__ __launch_bounds__(256) void prepack(Params P) {
    const int gid = blockIdx.x * 256 + threadIdx.x;
    const int cnt[10]  = {16384,16384,32768,16384,24576,8192,32768,32768,2048,2048};
    const int Ns [10]  = {512,256,1024,256,768,256,1024,256,24,512};
    const int NPs[10]  = {512,256,1024,256,768,256,1024,256,32,512};
    const int Ks [10]  = {256,512,256,512,256,256,256,1024,512,16};
    const int offs[10] = {OFF_GCN_W1,OFF_GCN_W2,OFF_INPROJ,OFF_OUTPROJ,OFF_QKV,
                          OFF_ATTNPROJ,OFF_MLP_W1,OFF_MLP_W2,OFF_XPROJ,OFF_DTW};
    int e = 0, base = 0;
    while (e < 10 && gid >= base + cnt[e]) { base += cnt[e]; ++e; }
    if (e >= 10) return;
    const float* W;
    switch (e) {
        case 0: W = P.gcn_w1; break;      case 1: W = P.gcn_w2; break;
        case 2: W = P.in_proj_w; break;   case 3: W = P.out_proj_w; break;
        case 4: W = P.qkv_w; break;       case 5: W = P.attn_proj_w; break;
        case 6: W = P.mlp_w1; break;      case 7: W = P.mlp_w2; break;
        case 8: W = P.x_proj_w; break;    default: W = P.dt_proj_w; break;
    }
    const int local = gid - base;
    const int lane = local & 63, frag = local >> 6;
    const int NT = NPs[e] >> 4;
    const int nt = frag % NT, kc = frag / NT;
    const int n = nt * 16 + (lane & 15);
    const int kbase = kc * 32 + (lane >> 4) * 8;
    u16 v[8];
    #pragma unroll
    for (int j = 0; j < 8; ++j)
        v[j] = (n < Ns[e] && kbase + j < Ks[e]) ? f2b(W[(size_t)(kbase + j) * Ns[e] + n]) : (u16)0;
    u16* dst = (u16*)P.wws + offs[e] + ((size_t)frag * 64 + lane) * 8;
    *(short8*)dst = *(short8*)v;
}

// ---------------- MFMA helpers: 3 M-tiles over 34 packed rows, 16 waves ----------------
template <int KT, int NT4>
__device__ __forceinline__ void mfmaAcc3(f32x4 acc[3][NT4],
        const u16* __restrict__ act, int ldin,
        const u16* __restrict__ wbase, int NT, int nt0, int ntcnt, int kc0) {
    const int lane = threadIdx.x & 63, wv = threadIdx.x >> 6;
    const int m = lane & 15, quad = lane >> 4;
    const bool v2 = (m < 2);
    #pragma unroll 1
    for (int kc = 0; kc < KT; ++kc) {
        const int ko = kc * 32 + quad * 8;
        short8 a0 = *(const short8*)(act + m * ldin + ko);
        short8 a1 = *(const short8*)(act + (16 + m) * ldin + ko);
        short8 a2 = {0,0,0,0,0,0,0,0};
        if (v2) a2 = *(const short8*)(act + (32 + m) * ldin + ko);
        #pragma unroll
        for (int i = 0; i < NT4; ++i) {
            const int ntl = wv + NWAVE * i;
            if (ntl < ntcnt) {
                const short8 b = *(const short8*)(wbase +
                    ((size_t)((kc0 + kc) * NT + nt0 + ntl) * 64 + lane) * 8);
                acc[0][i] = __builtin_amdgcn_mfma_f32_16x16x32_bf16(a0, b, acc[0][i], 0, 0, 0);
                acc[1][i] = __builtin_amdgcn_mfma_f32_16x16x32_bf16(a1, b, acc[1][i], 0, 0, 0);
                acc[2][i] = __builtin_amdgcn_mfma_f32_16x16x32_bf16(a2, b, acc[2][i], 0, 0, 0);
            }
        }
    }
}

// epi(rr, c_rel, val): rr in [0,34) packed row, c_rel relative to nt0*16.
template <int NT4, class Epi>
__device__ __forceinline__ void mfmaStore3(f32x4 acc[3][NT4], int ntcnt, Epi epi) {
    const int lane = threadIdx.x & 63, wv = threadIdx.x >> 6;
    const int col0 = lane & 15, quad = lane >> 4;
    #pragma unroll
    for (int i = 0; i < NT4; ++i) {
        const int ntl = wv + NWAVE * i;
        if (ntl < ntcnt) {
            const int cb = ntl * 16 + col0;
            #pragma unroll
            for (int r = 0; r < 4; ++r) epi(quad * 4 + r, cb, acc[0][i][r]);
            #pragma unroll
            for (int r = 0; r < 4; ++r) epi(16 + quad * 4 + r, cb, acc[1][i][r]);
            if (quad == 0) {
                epi(32, cb, acc[2][i][0]);
                epi(33, cb, acc[2][i][1]);
            }
        }
    }
}

template <int KT, int NT4, class Epi>
__device__ __forceinline__ void gemm3(const u16* act, int ldin,
        const u16* wbase, int NT, int nt0, int ntcnt, Epi epi) {
    f32x4 acc[3][NT4];
    #pragma unroll
    for (int mt = 0; mt < 3; ++mt)
        #pragma unroll
        for (int i = 0; i < NT4; ++i) acc[mt][i] = (f32x4){0.f,0.f,0.f,0.f};
    mfmaAcc3<KT, NT4>(acc, act, ldin, wbase, NT, nt0, ntcnt, 0);
    mfmaStore3<NT4>(acc, ntcnt, epi);
}

// ---------------- main fused kernel: 2 elements per block ----------------
__global__ __launch_bounds__(NTHR, 4) void fused_block(Params P) {
    extern __shared__ __align__(16) char smem[];
    float* R   = (float*)(smem + SM_R);    // [34][256] f32
    u16*   AC  = (u16*)  (smem + SM_AC);   // [34][264]
    u16*   T1  = (u16*)  (smem + SM_T1);   // [34][264]
    u16*   W5  = (u16*)  (smem + SM_W5);   // [34][520]
    float* Dbl = (float*)(smem + SM_U);    // [34][24] (mamba only)
    u16*   SC  = (u16*)  (smem + SM_U);    // [16][17][40] (attention only)
    u16*   DTI = (u16*)  (smem + SM_DTI);  // [34][32] (mamba only)
    u16*   DTO = (u16*)  (smem + SM_DTO);  // [34][512] (mamba only)
    u16*   VT  = (u16*)  (smem + SM_VT);   // [256][56] (attention V^T)

    const int tid = threadIdx.x;
    const int lane = tid & 63, wv = tid >> 6;
    const float* __restrict__ xg = P.x + (size_t)blockIdx.x * (2 * LSEQ * 256);
    const u16* __restrict__ ws = P.wws;

    // ln core: lane owns 4 consecutive cols d0..d0+3; v[] given, writes short4.
    auto lnStore = [&](float v[4], u16* dst, int rr, int d0,
                       const float* g, const float* bb) {
        float s = v[0] + v[1] + v[2] + v[3];
        float s2 = v[0]*v[0] + v[1]*v[1] + v[2]*v[2] + v[3]*v[3];
        #pragma unroll
        for (int m = 1; m < 64; m <<= 1) {
            s  += __shfl_xor(s, m, 64);
            s2 += __shfl_xor(s2, m, 64);
        }
        float mean = s * (1.0f / 256.0f);
        float var  = s2 * (1.0f / 256.0f) - mean * mean;
        float rstd = rsqrtf(var + 1e-5f);
        u16 o[4];
        #pragma unroll
        for (int j = 0; j < 4; ++j)
            o[j] = f2b((v[j] - mean) * rstd * g[d0 + j] + bb[d0 + j]);
        *(short4v*)(dst + rr * TS + d0) = *(short4v*)o;
    };
    auto ln34 = [&](auto ld, u16* dst, const float* g, const float* bb) {
        const int d0 = lane * 4;
        for (int rr = wv; rr < 34; rr += NWAVE) {
            float v[4];
            #pragma unroll
            for (int j = 0; j < 4; ++j) v[j] = ld(rr, d0 + j);
            lnStore(v, dst, rr, d0, g, bb);
        }
    };
    // sparse graph conv (49 nonzeros, compile-time weights); 2 threads/column
    auto gconvCols = [&](auto ldf, auto stf) {
        const int u = tid & 511, half = tid >> 9;
        const int e = u >> 8, d = u & 255;
        float c[17];
        #pragma unroll
        for (int j = 0; j < 17; ++j) c[j] = ldf(e, j, d);
        if (half == 0) {
            stf(e, 0, d, 0.25f*c[0] + 0.28867513f*(c[1]+c[4]+c[7]));
            stf(e, 1, d, 0.28867513f*c[0] + 0.33333334f*(c[1]+c[2]));
            stf(e, 2, d, 0.33333334f*(c[1]+c[2]) + 0.40824829f*c[3]);
            stf(e, 3, d, 0.40824829f*c[2] + 0.5f*c[3]);
            stf(e, 4, d, 0.28867513f*c[0] + 0.33333334f*(c[4]+c[5]));
            stf(e, 5, d, 0.33333334f*(c[4]+c[5]) + 0.40824829f*c[6]);
            stf(e, 6, d, 0.40824829f*c[5] + 0.5f*c[6]);
            stf(e, 7, d, 0.28867513f*c[0] + 0.33333334f*c[7] + 0.25819889f*c[8]);
            stf(e, 8, d, 0.25819889f*(c[7]+c[9]+c[11]+c[14]) + 0.2f*c[8]);
        } else {
            stf(e, 9, d, 0.25819889f*c[8] + 0.33333334f*c[9] + 0.40824829f*c[10]);
            stf(e,10, d, 0.40824829f*c[9] + 0.5f*c[10]);
            stf(e,11, d, 0.25819889f*c[8] + 0.33333334f*(c[11]+c[12]));
            stf(e,12, d, 0.33333334f*(c[11]+c[12]) + 0.40824829f*c[13]);
            stf(e,13, d, 0.40824829f*c[12] + 0.5f*c[13]);
            stf(e,14, d, 0.25819889f*c[8] + 0.33333334f*(c[14]+c[15]));
            stf(e,15, d, 0.33333334f*(c[14]+c[15]) + 0.40824829f*c[16]);
            stf(e,16, d, 0.40824829f*c[15] + 0.5f*c[16]);
        }
    };

    // ---------------- P0: x -> R fused with GCN ln -> AC ----------------
    {
        const int d0 = lane * 4;
        for (int rr = wv; rr < 34; rr += NWAVE) {
            f32x4 x4 = __builtin_nontemporal_load((const f32x4*)(xg + rr * 256 + d0));
            *(f32x4*)(R + rr * RS + d0) = x4;
            float v[4] = {x4[0], x4[1], x4[2], x4[3]};
            lnStore(v, AC, rr, d0, P.gcn_ln_g, P.gcn_ln_b);
        }
    }
    __syncthreads();

    // ---------------- GCN ----------------
    gconvCols(
        [&](int e, int j, int d) { return b2f(AC[(e * 17 + j) * TS + d]); },
        [&](int e, int i, int d, float v) { AC[(e * 17 + i) * TS + d] = f2b(v); });
    __syncthreads();
    gemm3<8, 2>(AC, TS, ws + OFF_GCN_W1, 32, 0, 32,
        [&](int rr, int c, float v) { W5[rr * SS + c] = f2b(gelu_t(v + P.gcn_b1[c])); });
    __syncthreads();
    // W2 first (commuted), raw result -> AC
    gemm3<16, 1>(W5, SS, ws + OFF_GCN_W2, 16, 0, 16,
        [&](int rr, int c, float v) { AC[rr * TS + c] = f2b(v); });
    __syncthreads();
    // gconv on 256 cols, fused +b2 and residual into R (x_a)
    gconvCols(
        [&](int e, int j, int d) { return b2f(AC[(e * 17 + j) * TS + d]); },
        [&](int e, int i, int d, float v) { R[(e * 17 + i) * RS + d] += v + P.gcn_b2[d]; });
    __syncthreads();

    // ---------------- Mamba ----------------
    // P5: hop-gather + bpe fused into ssm ln -> T1; zero DTI K-pad cols 16-31.
    {
        const int d0 = lane * 4;
        for (int rr = wv; rr < 34; rr += NWAVE) {
            int e = (rr >= 17), l = rr - e * 17;
            const float* rs = R + (e * 17 + HOPA[l]) * RS;
            const float* bp = P.bp_embed + BPEI[l] * 256;
            float v[4];
            #pragma unroll
            for (int j = 0; j < 4; ++j) v[j] = rs[d0 + j] + bp[d0 + j];
            lnStore(v, T1, rr, d0, P.ssm_ln_g, P.ssm_ln_b);
        }
        if (tid < 34 * 8) {
            int rr = tid >> 3, c2 = tid & 7;
            *(unsigned int*)(DTI + rr * 32 + 16 + c2 * 2) = 0u;
        }
    }
    __syncthreads();
    // xm = silu(conv(in_proj[:, :512])): one NT4=2 pass
    gemm3<8, 2>(T1, TS, ws + OFF_INPROJ, 64, 0, 32,
        [&](int rr, int c, float v) { W5[rr * SS + c] = f2b(siluf(v * P.conv_w[c] + P.conv_b[c])); });
    __syncthreads();
    // x_proj (N=24 padded to 32): dt-inputs -> DTI bf16, B/C -> Dbl f32
    gemm3<16, 1>(W5, SS, ws + OFF_XPROJ, 2, 0, 2,
        [&](int rr, int c, float v) {
            if (c < 16)      DTI[rr * 32 + c] = f2b(v);
            else if (c < 24) Dbl[rr * 24 + c] = v;
        });
    __syncthreads();
    // dt = softplus(DTI @ dt_proj_w + b) via MFMA -> DTO bf16
    gemm3<1, 2>(DTI, 32, ws + OFF_DTW, 32, 0, 32,
        [&](int rr, int c, float v) {
            DTO[rr * 512 + c] = f2b(softplusf(v + P.dt_proj_b[c]));
        });
    __syncthreads();
    // selective scan: thread owns (element e, channel d); dt precomputed
    {
        const int e = tid >> 9, d = tid & 511;
        const int rb = e * LSEQ;
        float Ar[4];
        #pragma unroll
        for (int s = 0; s < 4; ++s) Ar[s] = -__expf(P.A_log[d * 4 + s]);
        const float Dpd = P.Dp[d];
        float h0 = 0.f, h1 = 0.f, h2 = 0.f, h3 = 0.f;
        for (int t = 0; t < LSEQ; ++t) {
            const float* Dv = Dbl + (rb + t) * 24;
            float dt_ = b2f(DTO[(rb + t) * 512 + d]);
            float xm = b2f(W5[(rb + t) * SS + d]);
            float p = dt_ * xm;
            h0 = __expf(dt_ * Ar[0]) * h0 + p * Dv[16];
            h1 = __expf(dt_ * Ar[1]) * h1 + p * Dv[17];
            h2 = __expf(dt_ * Ar[2]) * h2 + p * Dv[18];
            h3 = __expf(dt_ * Ar[3]) * h3 + p * Dv[19];
            float y = h0 * Dv[20] + h1 * Dv[21] + h2 * Dv[22] + h3 * Dv[23] + Dpd * xm;
            W5[(rb + t) * SS + d] = f2b(y);
        }
    }
    __syncthreads();
    // z half of in_proj; gate y in place: one NT4=2 pass
    gemm3<8, 2>(T1, TS, ws + OFF_INPROJ, 64, 32, 32,
        [&](int rr, int c, float v) {
            float y = b2f(W5[rr * SS + c]);
            W5[rr * SS + c] = f2b(y * siluf(v));
        });
    __syncthreads();
    gemm3<16, 1>(W5, SS, ws + OFF_OUTPROJ, 16, 0, 16,
        [&](int rr, int c, float v) { AC[rr * TS + c] = f2b(v); });
    __syncthreads();

    // ---------------- Attention ----------------
    // P10: x_b scatter fused into ln1 -> T1 (x_b -> R); VT zeroing here too.
    {
        const int d0 = lane * 4;
        for (int rr = wv; rr < 34; rr += NWAVE) {
            int e = (rr >= 17), l = rr - e * 17;
            const u16* ms = AC + (e * 17 + GRAPHA[l]) * TS;
            float* rrow = R + rr * RS;
            float v[4];
            #pragma unroll
            for (int j = 0; j < 4; ++j) v[j] = 2.0f * rrow[d0 + j] + b2f(ms[d0 + j]);
            *(f32x4*)(rrow + d0) = (f32x4){v[0], v[1], v[2], v[3]};
            lnStore(v, T1, rr, d0, P.ln1_g, P.ln1_b);
        }
        for (int i = tid; i < (256 * VTS) / 2; i += NTHR)
            ((unsigned int*)VT)[i] = 0u;
    }
    __syncthreads();
    // QKV: pass1 NT4=2 covers Q+K (c 0..511), pass2 NT4=1 covers V -> VT.
    gemm3<8, 2>(T1, TS, ws + OFF_QKV, 48, 0, 32,
        [&](int rr, int c, float v) {
            if (c < 256) AC[rr * TS + c] = f2b(v);
            else         W5[rr * SS + (c - 256)] = f2b(v);
        });
    gemm3<8, 1>(T1, TS, ws + OFF_QKV, 48, 32, 16,
        [&](int rr, int c, float v) {
            int e2 = (rr >= 17), t = rr - e2 * 17;
            VT[c * VTS + e2 * 24 + t] = f2b(v);   // V^T: [chan][e*24 + t]
        });
    __syncthreads();
    // QK^T via MFMA: wave = (e, h). Q rows (AC) = A-frags, K rows (W5) = B-frags.
    {
        const int e = wv >> 3, h = wv & 7, m16 = lane & 15, quad = lane >> 4;
        const int rb = e * LSEQ;
        const u16* qb = AC + rb * TS + h * 32 + quad * 8;
        const u16* kb = W5 + rb * SS + h * 32 + quad * 8;
        short8 qa0 = *(const short8*)(qb + m16 * TS);
        short8 ka0 = *(const short8*)(kb + m16 * SS);
        short8 qa1 = {0,0,0,0,0,0,0,0}, ka1 = {0,0,0,0,0,0,0,0};
        if (m16 == 0) {
            qa1 = *(const short8*)(qb + 16 * TS);
            ka1 = *(const short8*)(kb + 16 * SS);
        }
        f32x4 s00 = {0.f,0.f,0.f,0.f}, s01 = s00, s10 = s00, s11 = s00;
        s00 = __builtin_amdgcn_mfma_f32_16x16x32_bf16(qa0, ka0, s00, 0, 0, 0);
        s01 = __builtin_amdgcn_mfma_f32_16x16x32_bf16(qa0, ka1, s01, 0, 0, 0);
        s10 = __builtin_amdgcn_mfma_f32_16x16x32_bf16(qa1, ka0, s10, 0, 0, 0);
        s11 = __builtin_amdgcn_mfma_f32_16x16x32_bf16(qa1, ka1, s11, 0, 0, 0);
        const float sc = 0.17677669529663687f;
        u16* sh = SC + wv * 17 * SCS;
        #pragma unroll
        for (int r = 0; r < 4; ++r) {
            int i = quad * 4 + r;
            sh[i * SCS + m16]      = f2b(s00[r] * sc);
            sh[i * SCS + 16 + m16] = f2b(s01[r] * sc);
        }
        if (quad == 0) {  // row 16 = C row 0 of the qa1 tile
            sh[16 * SCS + m16]      = f2b(s10[0] * sc);
            sh[16 * SCS + 16 + m16] = f2b(s11[0] * sc);
        }
    }
    __syncthreads();
    if (tid < 272) {  // 16 units x 17 rows
        u16* row = SC + tid * SCS;
        float e[17], mx = -3.0e38f, sum = 0.f;
        #pragma unroll
        for (int j = 0; j < 17; ++j) mx = fmaxf(mx, b2f(row[j]));
        #pragma unroll
        for (int j = 0; j < 17; ++j) { e[j] = __expf(b2f(row[j]) - mx); sum += e[j]; }
        float inv = 1.0f / sum;
        #pragma unroll
        for (int j = 0; j < 17; ++j) row[j] = f2b(e[j] * inv);
    }
    __syncthreads();
    // AV via MFMA: o -> AC (Q dead after QK^T).
    {
        const int e = wv >> 3, h = wv & 7, m16 = lane & 15, quad = lane >> 4;
        const int rb = e * LSEQ;
        const u16* sh = SC + wv * 17 * SCS + quad * 8;
        short8 pa0 = *(const short8*)(sh + m16 * SCS);
        short8 pa1 = {0,0,0,0,0,0,0,0};
        if (m16 == 0) pa1 = *(const short8*)(sh + 16 * SCS);
        #pragma unroll
        for (int nt = 0; nt < 2; ++nt) {
            const int n = h * 32 + nt * 16 + m16;
            short8 vb = {0,0,0,0,0,0,0,0};
            if (quad < 3) vb = *(const short8*)(VT + n * VTS + e * 24 + quad * 8);
            f32x4 o0 = {0.f,0.f,0.f,0.f}, o1 = o0;
            o0 = __builtin_amdgcn_mfma_f32_16x16x32_bf16(pa0, vb, o0, 0, 0, 0);
            o1 = __builtin_amdgcn_mfma_f32_16x16x32_bf16(pa1, vb, o1, 0, 0, 0);
            #pragma unroll
            for (int r = 0; r < 4; ++r) {
                int i = quad * 4 + r;
                AC[(rb + i) * TS + h * 32 + nt * 16 + m16] = f2b(o0[r]);
            }
            if (quad == 0)
                AC[(rb + 16) * TS + h * 32 + nt * 16 + m16] = f2b(o1[0]);
        }
    }
    __syncthreads();
    // o' = attn_proj(o) + bias -> T1 (ln1-out dead after QKV)
    gemm3<8, 1>(AC, TS, ws + OFF_ATTNPROJ, 16, 0, 16,
        [&](int rr, int c, float v) { T1[rr * TS + c] = f2b(v + P.attn_proj_b[c]); });
    __syncthreads();

    // ---------------- MLP + final ----------------
    ln34([&](int rr, int d) { return R[rr * RS + d] + b2f(T1[rr * TS + d]); },
         AC, P.ln2_g, P.ln2_b);
    __syncthreads();
    {
        f32x4 accO[3][1];
        #pragma unroll
        for (int mt = 0; mt < 3; ++mt) accO[mt][0] = (f32x4){0.f,0.f,0.f,0.f};
        #pragma unroll
        for (int half = 0; half < 2; ++half) {
            gemm3<8, 2>(AC, TS, ws + OFF_MLP_W1, 64, half * 32, 32,
                [&](int rr, int c, float v) {
                    W5[rr * SS + c] = f2b(gelu_t(v + P.mlp_b1[half * 512 + c]));
                });
            __syncthreads();
            mfmaAcc3<16, 1>(accO, W5, SS, ws + OFF_MLP_W2, 16, 0, 16, half * 16);
            __syncthreads();  // W5 reused next half
        }
        float* outg = P.out + (size_t)blockIdx.x * (2 * LSEQ * 256);
        mfmaStore3<1>(accO, 16, [&](int rr, int c, float v) {
            float r = v + P.mlp_b2[c] + 2.0f * R[rr * RS + c] + b2f(T1[rr * TS + c]);
            __builtin_nontemporal_store(r, outg + rr * 256 + c);
        });
    }
}

extern "C" void kernel_launch(void* const* d_in, const int* in_sizes, int n_in,
                              void* d_out, int out_size, void* d_ws, size_t ws_size,
                              hipStream_t stream) {
    (void)in_sizes; (void)n_in; (void)ws_size; (void)out_size;
    Params P;
    P.x           = (const float*)d_in[0];
    P.gcn_ln_g    = (const float*)d_in[1];
    P.gcn_ln_b    = (const float*)d_in[2];
    P.gcn_w1      = (const float*)d_in[3];
    P.gcn_b1      = (const float*)d_in[4];
    P.gcn_w2      = (const float*)d_in[5];
    P.gcn_b2      = (const float*)d_in[6];
    P.bp_embed    = (const float*)d_in[7];
    P.ssm_ln_g    = (const float*)d_in[8];
    P.ssm_ln_b    = (const float*)d_in[9];
    P.in_proj_w   = (const float*)d_in[10];
    P.conv_w      = (const float*)d_in[11];
    P.conv_b      = (const float*)d_in[12];
    P.x_proj_w    = (const float*)d_in[13];
    P.dt_proj_w   = (const float*)d_in[14];
    P.dt_proj_b   = (const float*)d_in[15];
    P.A_log       = (const float*)d_in[16];
    P.Dp          = (const float*)d_in[17];
    P.out_proj_w  = (const float*)d_in[18];
    P.ln1_g       = (const float*)d_in[19];
    P.ln1_b       = (const float*)d_in[20];
    P.qkv_w       = (const float*)d_in[21];
    P.attn_proj_w = (const float*)d_in[22];
    P.attn_proj_b = (const float*)d_in[23];
    P.ln2_g       = (const float*)d_in[24];
    P.ln2_b       = (const float*)d_in[25];
    P.mlp_w1      = (const float*)d_in[26];
    P.mlp_b1      = (const float*)d_in[27];
    P.mlp_w2      = (const float*)d_in[28];
    P.mlp_b2      = (const float*)d_in[29];
    P.wws         = (const u16*)d_ws;
    P.out         = (float*)d_out;
    static int smem_set = 0;
    if (!smem_set) {
        hipFuncSetAttribute(reinterpret_cast<const void*>(fused_block),
                            hipFuncAttributeMaxDynamicSharedMemorySize, SMEM_BYTES);
        smem_set = 1;
    }
    hipLaunchKernelGGL(prepack, dim3(720), dim3(256), 0, stream, P);
    hipLaunchKernelGGL(fused_block, dim3(2048), dim3(NTHR), SMEM_BYTES, stream, P);
}